// Round 1
// baseline (2219.887 us; speedup 1.0000x reference)
//
#include <hip/hip_runtime.h>
#include <hip/hip_bf16.h>

// Shapes (compile-time constants from the reference)
#define BATCH 1
#define NTOK 4096
#define EMB 1024
#define DMODEL 512
#define NHEAD 8
#define HDIM 64
#define NLAYER 2
#define NCLS 2
#define KMAX 160

__device__ inline float wsum(float v) {
    for (int o = 32; o > 0; o >>= 1) v += __shfl_xor(v, o, 64);
    return v;
}
__device__ inline float wmax(float v) {
    for (int o = 32; o > 0; o >>= 1) v = fmaxf(v, __shfl_xor(v, o, 64));
    return v;
}

// ---------------- GEMM: C = epilogue(A[M,K] @ W[K,N] + bias) ----------------
// MODE 0: C = AW+b
// MODE 1: C = resid + relu(AW+b)
// MODE 2: C = gelu_tanh(AW+b)
// MODE 3: C = resid + AW + b   (resid may alias C; A must differ from C)
#define BM 64
#define BN 64
#define BK 16

template <int MODE>
__global__ __launch_bounds__(256) void gemm_k(
    const float* __restrict__ A, const float* __restrict__ W,
    const float* __restrict__ bias, const float* resid, float* C,
    int M, int N, int K)
{
    __shared__ float As[BK][BM + 4];
    __shared__ float Bs[BK][BN + 4];
    int tid = threadIdx.x;
    int tx = tid & 15, ty = tid >> 4;
    int bm = blockIdx.x * BM, bn = blockIdx.y * BN;

    float acc[4][4] = {};

    int arow = tid >> 2;          // 0..63
    int acol = (tid & 3) * 4;     // 0,4,8,12
    int brow = tid >> 4;          // 0..15
    int bcol = (tid & 15) * 4;    // 0..60

    const float* Aptr = A + (size_t)(bm + arow) * K + acol;
    const float* Bptr = W + (size_t)brow * N + bn + bcol;

    for (int k0 = 0; k0 < K; k0 += BK) {
        float4 a4 = *(const float4*)(Aptr + k0);
        float4 b4 = *(const float4*)(Bptr + (size_t)k0 * N);
        As[acol + 0][arow] = a4.x;
        As[acol + 1][arow] = a4.y;
        As[acol + 2][arow] = a4.z;
        As[acol + 3][arow] = a4.w;
        *(float4*)&Bs[brow][bcol] = b4;
        __syncthreads();
#pragma unroll
        for (int kk = 0; kk < BK; kk++) {
            float4 av = *(const float4*)&As[kk][ty * 4];
            float4 bv = *(const float4*)&Bs[kk][tx * 4];
            acc[0][0] += av.x * bv.x; acc[0][1] += av.x * bv.y; acc[0][2] += av.x * bv.z; acc[0][3] += av.x * bv.w;
            acc[1][0] += av.y * bv.x; acc[1][1] += av.y * bv.y; acc[1][2] += av.y * bv.z; acc[1][3] += av.y * bv.w;
            acc[2][0] += av.z * bv.x; acc[2][1] += av.z * bv.y; acc[2][2] += av.z * bv.z; acc[2][3] += av.z * bv.w;
            acc[3][0] += av.w * bv.x; acc[3][1] += av.w * bv.y; acc[3][2] += av.w * bv.z; acc[3][3] += av.w * bv.w;
        }
        __syncthreads();
    }

#pragma unroll
    for (int i = 0; i < 4; i++) {
        int r = bm + ty * 4 + i;
        size_t rowoff = (size_t)r * N + bn + tx * 4;
#pragma unroll
        for (int j = 0; j < 4; j++) {
            float v = acc[i][j] + bias[bn + tx * 4 + j];
            if (MODE == 0) {
                C[rowoff + j] = v;
            } else if (MODE == 1) {
                C[rowoff + j] = resid[rowoff + j] + fmaxf(v, 0.f);
            } else if (MODE == 2) {
                float t = tanhf(0.7978845608028654f * (v + 0.044715f * v * v * v));
                C[rowoff + j] = 0.5f * v * (1.f + t);
            } else {
                C[rowoff + j] = resid[rowoff + j] + v;
            }
        }
    }
}

// ---------------- LayerNorm over D=512, one row per block ----------------
__global__ __launch_bounds__(256) void ln_k(
    const float* __restrict__ X, const float* __restrict__ g,
    const float* __restrict__ bta, float* __restrict__ Y, float eps)
{
    int row = blockIdx.x;
    int tid = threadIdx.x;
    const float* xr = X + (size_t)row * DMODEL;
    float v0 = xr[tid], v1 = xr[tid + 256];
    __shared__ float red[8];
    float s = wsum(v0 + v1);
    int wid = tid >> 6, lane = tid & 63;
    if (lane == 0) red[wid] = s;
    __syncthreads();
    float m = (red[0] + red[1] + red[2] + red[3]) * (1.f / DMODEL);
    float d0 = v0 - m, d1 = v1 - m;
    float sq = wsum(d0 * d0 + d1 * d1);
    if (lane == 0) red[4 + wid] = sq;
    __syncthreads();
    float var = (red[4] + red[5] + red[6] + red[7]) * (1.f / DMODEL);
    float rs = 1.0f / sqrtf(var + eps);
    Y[(size_t)row * DMODEL + tid] = d0 * rs * g[tid] + bta[tid];
    Y[(size_t)row * DMODEL + tid + 256] = d1 * rs * g[tid + 256] + bta[tid + 256];
}

// ---------------- kn[n,h] = sum_d k[n,h,d]^2 ----------------
__global__ __launch_bounds__(512) void kn_k(const float* __restrict__ qkv, float* __restrict__ kn)
{
    int n = blockIdx.x;
    int hh = threadIdx.x >> 6, lane = threadIdx.x & 63;
    float kv = qkv[(size_t)n * 1536 + 512 + hh * 64 + lane];
    float ks = wsum(kv * kv);
    if (lane == 0) kn[n * NHEAD + hh] = ks;
}

// ---------------- gathered attention: one wave per (n, head) ----------------
__global__ __launch_bounds__(64) void attn_k(
    const float* __restrict__ qkv, const float* __restrict__ kn,
    const int* __restrict__ indices, const float* __restrict__ distance,
    const float* __restrict__ lam, float* __restrict__ xo, int layer)
{
    int id = blockIdx.x;
    int n = id >> 3, hh = id & 7;
    int Kh = 32 + 16 * hh + (hh == 7 ? 16 : 0);
    int lane = threadIdx.x;

    float qd = qkv[(size_t)n * 1536 + hh * 64 + lane];
    float qn2 = wsum(qd * qd);
    float sp = log1pf(expf(lam[layer * NHEAD + hh]));

    __shared__ float ssc[KMAX];
    __shared__ int six[KMAX];
    const int* irow = indices + (size_t)n * KMAX;
    const float* drow = distance + (size_t)n * NTOK;

    for (int k = 0; k < Kh; k++) {
        int idx = irow[k];
        float kd = qkv[(size_t)idx * 1536 + 512 + hh * 64 + lane];
        float dot = wsum(qd * kd);
        if (lane == 0) {
            float knv = kn[idx * NHEAD + hh];
            float dist = drow[idx];
            float dec = expf(-sp * dist) + 1e-6f;
            ssc[k] = (dot - 0.5f * (qn2 + knv)) * 0.125f + logf(dec);
            six[k] = idx;
        }
    }
    __syncthreads();

    // softmax over Kh entries (<= 160 = 3 per lane)
    float v[3];
    float mx = -1e30f;
#pragma unroll
    for (int j = 0; j < 3; j++) {
        int kk = lane + j * 64;
        v[j] = (kk < Kh) ? ssc[kk] : -1e30f;
        mx = fmaxf(mx, v[j]);
    }
    mx = wmax(mx);
    float se = 0.f;
#pragma unroll
    for (int j = 0; j < 3; j++) {
        int kk = lane + j * 64;
        if (kk < Kh) { v[j] = expf(v[j] - mx); se += v[j]; }
    }
    se = wsum(se);
    float inv = 1.f / se;
    __syncthreads();
#pragma unroll
    for (int j = 0; j < 3; j++) {
        int kk = lane + j * 64;
        if (kk < Kh) ssc[kk] = v[j] * inv;
    }
    __syncthreads();

    float acc = 0.f;
    for (int k = 0; k < Kh; k++) {
        float a = ssc[k];
        int idx = six[k];
        acc += a * qkv[(size_t)idx * 1536 + 1024 + hh * 64 + lane];
    }
    xo[(size_t)n * DMODEL + hh * 64 + lane] = acc;
}

// ---------------- column partial sums of Y (4096 x 512): 16 rows per block ----------------
__global__ __launch_bounds__(512) void colpart_k(const float* __restrict__ Y, float* __restrict__ part)
{
    int c = threadIdx.x;
    int blk = blockIdx.x;
    const float* p = Y + (size_t)blk * 16 * DMODEL + c;
    float s = 0.f;
#pragma unroll
    for (int r = 0; r < 16; r++) s += p[r * DMODEL];
    part[blk * DMODEL + c] = s;
}

// ---------------- finish mean + head GEMV ----------------
__global__ __launch_bounds__(512) void finhead_k(
    const float* __restrict__ part, const float* __restrict__ head_w,
    const float* __restrict__ head_b, float* __restrict__ out)
{
    __shared__ float mv[DMODEL];
    int c = threadIdx.x;
    float s = 0.f;
    for (int i = 0; i < 256; i++) s += part[i * DMODEL + c];
    mv[c] = s * (1.f / NTOK);
    __syncthreads();
    if (c < 64) {
        float a0 = 0.f, a1 = 0.f;
        for (int d = c; d < DMODEL; d += 64) {
            float m = mv[d];
            a0 += m * head_w[d * NCLS + 0];
            a1 += m * head_w[d * NCLS + 1];
        }
        a0 = wsum(a0);
        a1 = wsum(a1);
        if (c == 0) { out[0] = a0 + head_b[0]; out[1] = a1 + head_b[1]; }
    }
}

extern "C" void kernel_launch(void* const* d_in, const int* in_sizes, int n_in,
                              void* d_out, int out_size, void* d_ws, size_t ws_size,
                              hipStream_t stream)
{
    const float* x        = (const float*)d_in[0];
    const float* distance = (const float*)d_in[1];
    const int*   indices  = (const int*)d_in[2];
    // d_in[3] row, d_in[4] col: unused in forward
    const float* adapter_w = (const float*)d_in[5];
    const float* adapter_b = (const float*)d_in[6];
    const float* res_w     = (const float*)d_in[7];
    const float* res_b     = (const float*)d_in[8];
    const float* ln1_g     = (const float*)d_in[9];
    const float* ln1_b     = (const float*)d_in[10];
    const float* qkv_w     = (const float*)d_in[11];
    const float* qkv_b     = (const float*)d_in[12];
    const float* proj_w    = (const float*)d_in[13];
    const float* proj_b    = (const float*)d_in[14];
    const float* ln2_g     = (const float*)d_in[15];
    const float* ln2_b     = (const float*)d_in[16];
    const float* fc1_w     = (const float*)d_in[17];
    const float* fc1_b     = (const float*)d_in[18];
    const float* fc2_w     = (const float*)d_in[19];
    const float* fc2_b     = (const float*)d_in[20];
    const float* lam       = (const float*)d_in[21];
    const float* lnf_g     = (const float*)d_in[22];
    const float* lnf_b     = (const float*)d_in[23];
    const float* head_w    = (const float*)d_in[24];
    const float* head_b    = (const float*)d_in[25];
    float* out = (float*)d_out;

    float* ws = (float*)d_ws;
    // workspace layout (floats)
    float* xa   = ws;                       // 2,097,152 (also adapter temp)
    float* h    = ws + 2097152;             // 2,097,152
    float* qkvb = ws + 4194304;             // 6,291,456 (fc1b aliases: 8,388,608)
    float* fc1b = qkvb;
    float* xo   = ws + 12582912;            // 2,097,152
    float* kn   = ws + 14680064;            // 32,768
    float* part = ws + 14712832;            // 131,072

    dim3 blk(256);

    // h0 = x @ adapter_w + b  (into xa)
    gemm_k<0><<<dim3(NTOK / BM, DMODEL / BN), blk, 0, stream>>>(
        x, adapter_w, adapter_b, nullptr, xa, NTOK, DMODEL, EMB);
    // h = h0 + relu(h0 @ res_w + b)
    gemm_k<1><<<dim3(NTOK / BM, DMODEL / BN), blk, 0, stream>>>(
        xa, res_w, res_b, xa, h, NTOK, DMODEL, DMODEL);

    for (int l = 0; l < NLAYER; l++) {
        ln_k<<<NTOK, blk, 0, stream>>>(h, ln1_g + l * DMODEL, ln1_b + l * DMODEL, xa, 1e-5f);
        gemm_k<0><<<dim3(NTOK / BM, (3 * DMODEL) / BN), blk, 0, stream>>>(
            xa, qkv_w + (size_t)l * DMODEL * 3 * DMODEL, qkv_b + l * 3 * DMODEL,
            nullptr, qkvb, NTOK, 3 * DMODEL, DMODEL);
        kn_k<<<NTOK, 512, 0, stream>>>(qkvb, kn);
        attn_k<<<NTOK * NHEAD, 64, 0, stream>>>(qkvb, kn, indices, distance, lam, xo, l);
        gemm_k<3><<<dim3(NTOK / BM, DMODEL / BN), blk, 0, stream>>>(
            xo, proj_w + (size_t)l * DMODEL * DMODEL, proj_b + l * DMODEL, h, h,
            NTOK, DMODEL, DMODEL);
        ln_k<<<NTOK, blk, 0, stream>>>(h, ln2_g + l * DMODEL, ln2_b + l * DMODEL, xa, 1e-5f);
        gemm_k<2><<<dim3(NTOK / BM, (4 * DMODEL) / BN), blk, 0, stream>>>(
            xa, fc1_w + (size_t)l * DMODEL * 4 * DMODEL, fc1_b + l * 4 * DMODEL,
            nullptr, fc1b, NTOK, 4 * DMODEL, DMODEL);
        gemm_k<3><<<dim3(NTOK / BM, DMODEL / BN), blk, 0, stream>>>(
            fc1b, fc2_w + (size_t)l * 4 * DMODEL * DMODEL, fc2_b + l * DMODEL, h, h,
            NTOK, DMODEL, 4 * DMODEL);
    }

    ln_k<<<NTOK, blk, 0, stream>>>(h, lnf_g, lnf_b, xa, 1e-6f);
    colpart_k<<<256, 512, 0, stream>>>(xa, part);
    finhead_k<<<1, 512, 0, stream>>>(part, head_w, head_b, out);
}

// Round 2
// 1345.845 us; speedup vs baseline: 1.6494x; 1.6494x over previous
//
#include <hip/hip_runtime.h>
#include <hip/hip_bf16.h>

// Shapes (compile-time constants from the reference)
#define BATCH 1
#define NTOK 4096
#define EMB 1024
#define DMODEL 512
#define NHEAD 8
#define HDIM 64
#define NLAYER 2
#define NCLS 2
#define KMAX 160

__device__ inline float wsum(float v) {
    for (int o = 32; o > 0; o >>= 1) v += __shfl_xor(v, o, 64);
    return v;
}
__device__ inline float wmax(float v) {
    for (int o = 32; o > 0; o >>= 1) v = fmaxf(v, __shfl_xor(v, o, 64));
    return v;
}

// ---------------- GEMM: C = epilogue(A[M,K] @ W[K,N] + bias) ----------------
// MODE 0: C = AW+b
// MODE 1: C = resid + relu(AW+b)
// MODE 2: C = gelu_tanh(AW+b)
// MODE 3: C = resid + AW + b   (resid may alias C; A must differ from C)
#define BM 64
#define BN 64
#define BK 16

template <int MODE>
__global__ __launch_bounds__(256) void gemm_k(
    const float* __restrict__ A, const float* __restrict__ W,
    const float* __restrict__ bias, const float* resid, float* C,
    int M, int N, int K)
{
    __shared__ float As[BK][BM + 4];
    __shared__ float Bs[BK][BN + 4];
    int tid = threadIdx.x;
    int tx = tid & 15, ty = tid >> 4;
    int bm = blockIdx.x * BM, bn = blockIdx.y * BN;

    float acc[4][4] = {};

    int arow = tid >> 2;          // 0..63
    int acol = (tid & 3) * 4;     // 0,4,8,12
    int brow = tid >> 4;          // 0..15
    int bcol = (tid & 15) * 4;    // 0..60

    const float* Aptr = A + (size_t)(bm + arow) * K + acol;
    const float* Bptr = W + (size_t)brow * N + bn + bcol;

    for (int k0 = 0; k0 < K; k0 += BK) {
        float4 a4 = *(const float4*)(Aptr + k0);
        float4 b4 = *(const float4*)(Bptr + (size_t)k0 * N);
        As[acol + 0][arow] = a4.x;
        As[acol + 1][arow] = a4.y;
        As[acol + 2][arow] = a4.z;
        As[acol + 3][arow] = a4.w;
        *(float4*)&Bs[brow][bcol] = b4;
        __syncthreads();
#pragma unroll
        for (int kk = 0; kk < BK; kk++) {
            float4 av = *(const float4*)&As[kk][ty * 4];
            float4 bv = *(const float4*)&Bs[kk][tx * 4];
            acc[0][0] += av.x * bv.x; acc[0][1] += av.x * bv.y; acc[0][2] += av.x * bv.z; acc[0][3] += av.x * bv.w;
            acc[1][0] += av.y * bv.x; acc[1][1] += av.y * bv.y; acc[1][2] += av.y * bv.z; acc[1][3] += av.y * bv.w;
            acc[2][0] += av.z * bv.x; acc[2][1] += av.z * bv.y; acc[2][2] += av.z * bv.z; acc[2][3] += av.z * bv.w;
            acc[3][0] += av.w * bv.x; acc[3][1] += av.w * bv.y; acc[3][2] += av.w * bv.z; acc[3][3] += av.w * bv.w;
        }
        __syncthreads();
    }

#pragma unroll
    for (int i = 0; i < 4; i++) {
        int r = bm + ty * 4 + i;
        size_t rowoff = (size_t)r * N + bn + tx * 4;
#pragma unroll
        for (int j = 0; j < 4; j++) {
            float v = acc[i][j] + bias[bn + tx * 4 + j];
            if (MODE == 0) {
                C[rowoff + j] = v;
            } else if (MODE == 1) {
                C[rowoff + j] = resid[rowoff + j] + fmaxf(v, 0.f);
            } else if (MODE == 2) {
                float t = tanhf(0.7978845608028654f * (v + 0.044715f * v * v * v));
                C[rowoff + j] = 0.5f * v * (1.f + t);
            } else {
                C[rowoff + j] = resid[rowoff + j] + v;
            }
        }
    }
}

// ---------------- LayerNorm over D=512, one row per block ----------------
__global__ __launch_bounds__(256) void ln_k(
    const float* __restrict__ X, const float* __restrict__ g,
    const float* __restrict__ bta, float* __restrict__ Y, float eps)
{
    int row = blockIdx.x;
    int tid = threadIdx.x;
    const float* xr = X + (size_t)row * DMODEL;
    float v0 = xr[tid], v1 = xr[tid + 256];
    __shared__ float red[8];
    float s = wsum(v0 + v1);
    int wid = tid >> 6, lane = tid & 63;
    if (lane == 0) red[wid] = s;
    __syncthreads();
    float m = (red[0] + red[1] + red[2] + red[3]) * (1.f / DMODEL);
    float d0 = v0 - m, d1 = v1 - m;
    float sq = wsum(d0 * d0 + d1 * d1);
    if (lane == 0) red[4 + wid] = sq;
    __syncthreads();
    float var = (red[4] + red[5] + red[6] + red[7]) * (1.f / DMODEL);
    float rs = 1.0f / sqrtf(var + eps);
    Y[(size_t)row * DMODEL + tid] = d0 * rs * g[tid] + bta[tid];
    Y[(size_t)row * DMODEL + tid + 256] = d1 * rs * g[tid + 256] + bta[tid + 256];
}

// ---------------- kn[n,h] = sum_d k[n,h,d]^2 ----------------
__global__ __launch_bounds__(512) void kn_k(const float* __restrict__ qkv, float* __restrict__ kn)
{
    int n = blockIdx.x;
    int hh = threadIdx.x >> 6, lane = threadIdx.x & 63;
    float kv = qkv[(size_t)n * 1536 + 512 + hh * 64 + lane];
    float ks = wsum(kv * kv);
    if (lane == 0) kn[n * NHEAD + hh] = ks;
}

// ---------------- gathered attention: one wave per (n, head), 4 waves/block --------
// Phase A: lane-per-neighbor score computation (no shuffles, 16 float4 loads/lane)
// Phase B: register softmax (wave reduce)
// Phase C: LDS-transposed PV with lane-per-dim coalesced V loads, 8-deep load pipeline
__global__ __launch_bounds__(256) void attn_k(
    const float* __restrict__ qkv, const float* __restrict__ kn,
    const int* __restrict__ indices, const float* __restrict__ distance,
    const float* __restrict__ lam, float* __restrict__ xo, int layer)
{
    int wid = threadIdx.x >> 6, lane = threadIdx.x & 63;
    int id = blockIdx.x * 4 + wid;
    int n = id >> 3, hh = id & 7;
    int Kh = 32 + 16 * hh + (hh == 7 ? 16 : 0);   // 32,48,64,80,96,112,128,160

    __shared__ __align__(16) float qs[4][64];
    __shared__ float asc[4][KMAX];
    __shared__ int   sidx[4][KMAX];

    const float* qrow = qkv + (size_t)n * 1536 + hh * 64;
    float qd = qrow[lane];
    qs[wid][lane] = qd;
    float qn2 = wsum(qd * qd);
    float sp = log1pf(expf(lam[layer * NHEAD + hh]));

    const int* irow = indices + (size_t)n * KMAX;
    const float* drow = distance + (size_t)n * NTOK;

    // ---- Phase A: scores, lane kk = j*64 + lane ----
    float sc[3];
    int   sid[3];
#pragma unroll
    for (int j = 0; j < 3; j++) { sc[j] = -1e30f; sid[j] = 0; }

    const float4* q4 = (const float4*)&qs[wid][0];
#pragma unroll
    for (int j = 0; j < 3; j++) {
        if (j * 64 >= Kh) break;            // wave-uniform
        int kk = j * 64 + lane;
        bool ok = kk < Kh;
        int idx = ok ? irow[kk] : 0;
        sid[j] = idx;
        const float4* krow = (const float4*)(qkv + (size_t)idx * 1536 + 512 + hh * 64);
        float dot = 0.f;
#pragma unroll
        for (int d = 0; d < 16; d++) {
            float4 kv = krow[d];
            float4 qv = q4[d];
            dot += qv.x * kv.x + qv.y * kv.y + qv.z * kv.z + qv.w * kv.w;
        }
        float knv = kn[idx * NHEAD + hh];
        float dist = drow[idx];
        float dec = expf(-sp * dist) + 1e-6f;
        float s = (dot - 0.5f * (qn2 + knv)) * 0.125f + logf(dec);
        sc[j] = ok ? s : -1e30f;
    }

    // ---- Phase B: softmax in registers ----
    float mx = fmaxf(fmaxf(sc[0], sc[1]), sc[2]);
    mx = wmax(mx);
    float se = 0.f;
#pragma unroll
    for (int j = 0; j < 3; j++) {
        float e = (sc[j] > -1e29f) ? expf(sc[j] - mx) : 0.f;
        sc[j] = e;
        se += e;
    }
    se = wsum(se);
    float inv = 1.f / se;

#pragma unroll
    for (int j = 0; j < 3; j++) {
        int kk = j * 64 + lane;
        if (kk < Kh) {
            asc[wid][kk] = sc[j] * inv;
            sidx[wid][kk] = sid[j];
        }
    }
    // waves are independent; same-wave LDS write->read ordering is handled by waitcnt

    // ---- Phase C: PV, lane = d, 8-deep pipelined ----
    float acc = 0.f;
    const float* vbase = qkv + 1024 + hh * 64 + lane;
    for (int k0 = 0; k0 < Kh; k0 += 8) {
        float vv[8], aa[8];
        int ii[8];
#pragma unroll
        for (int u = 0; u < 8; u++) { ii[u] = sidx[wid][k0 + u]; aa[u] = asc[wid][k0 + u]; }
#pragma unroll
        for (int u = 0; u < 8; u++) vv[u] = vbase[(size_t)ii[u] * 1536];
#pragma unroll
        for (int u = 0; u < 8; u++) acc += aa[u] * vv[u];
    }
    xo[(size_t)n * DMODEL + hh * 64 + lane] = acc;
}

// ---------------- column partial sums of Y (4096 x 512): 16 rows per block ----------------
__global__ __launch_bounds__(512) void colpart_k(const float* __restrict__ Y, float* __restrict__ part)
{
    int c = threadIdx.x;
    int blk = blockIdx.x;
    const float* p = Y + (size_t)blk * 16 * DMODEL + c;
    float s = 0.f;
#pragma unroll
    for (int r = 0; r < 16; r++) s += p[r * DMODEL];
    part[blk * DMODEL + c] = s;
}

// ---------------- finish mean + head GEMV ----------------
__global__ __launch_bounds__(512) void finhead_k(
    const float* __restrict__ part, const float* __restrict__ head_w,
    const float* __restrict__ head_b, float* __restrict__ out)
{
    __shared__ float mv[DMODEL];
    int c = threadIdx.x;
    float s = 0.f;
    for (int i = 0; i < 256; i++) s += part[i * DMODEL + c];
    mv[c] = s * (1.f / NTOK);
    __syncthreads();
    if (c < 64) {
        float a0 = 0.f, a1 = 0.f;
        for (int d = c; d < DMODEL; d += 64) {
            float m = mv[d];
            a0 += m * head_w[d * NCLS + 0];
            a1 += m * head_w[d * NCLS + 1];
        }
        a0 = wsum(a0);
        a1 = wsum(a1);
        if (c == 0) { out[0] = a0 + head_b[0]; out[1] = a1 + head_b[1]; }
    }
}

extern "C" void kernel_launch(void* const* d_in, const int* in_sizes, int n_in,
                              void* d_out, int out_size, void* d_ws, size_t ws_size,
                              hipStream_t stream)
{
    const float* x        = (const float*)d_in[0];
    const float* distance = (const float*)d_in[1];
    const int*   indices  = (const int*)d_in[2];
    // d_in[3] row, d_in[4] col: unused in forward
    const float* adapter_w = (const float*)d_in[5];
    const float* adapter_b = (const float*)d_in[6];
    const float* res_w     = (const float*)d_in[7];
    const float* res_b     = (const float*)d_in[8];
    const float* ln1_g     = (const float*)d_in[9];
    const float* ln1_b     = (const float*)d_in[10];
    const float* qkv_w     = (const float*)d_in[11];
    const float* qkv_b     = (const float*)d_in[12];
    const float* proj_w    = (const float*)d_in[13];
    const float* proj_b    = (const float*)d_in[14];
    const float* ln2_g     = (const float*)d_in[15];
    const float* ln2_b     = (const float*)d_in[16];
    const float* fc1_w     = (const float*)d_in[17];
    const float* fc1_b     = (const float*)d_in[18];
    const float* fc2_w     = (const float*)d_in[19];
    const float* fc2_b     = (const float*)d_in[20];
    const float* lam       = (const float*)d_in[21];
    const float* lnf_g     = (const float*)d_in[22];
    const float* lnf_b     = (const float*)d_in[23];
    const float* head_w    = (const float*)d_in[24];
    const float* head_b    = (const float*)d_in[25];
    float* out = (float*)d_out;

    float* ws = (float*)d_ws;
    // workspace layout (floats)
    float* xa   = ws;                       // 2,097,152 (also adapter temp)
    float* h    = ws + 2097152;             // 2,097,152
    float* qkvb = ws + 4194304;             // 6,291,456 (fc1b aliases: 8,388,608)
    float* fc1b = qkvb;
    float* xo   = ws + 12582912;            // 2,097,152
    float* kn   = ws + 14680064;            // 32,768
    float* part = ws + 14712832;            // 131,072

    dim3 blk(256);

    // h0 = x @ adapter_w + b  (into xa)
    gemm_k<0><<<dim3(NTOK / BM, DMODEL / BN), blk, 0, stream>>>(
        x, adapter_w, adapter_b, nullptr, xa, NTOK, DMODEL, EMB);
    // h = h0 + relu(h0 @ res_w + b)
    gemm_k<1><<<dim3(NTOK / BM, DMODEL / BN), blk, 0, stream>>>(
        xa, res_w, res_b, xa, h, NTOK, DMODEL, DMODEL);

    for (int l = 0; l < NLAYER; l++) {
        ln_k<<<NTOK, blk, 0, stream>>>(h, ln1_g + l * DMODEL, ln1_b + l * DMODEL, xa, 1e-5f);
        gemm_k<0><<<dim3(NTOK / BM, (3 * DMODEL) / BN), blk, 0, stream>>>(
            xa, qkv_w + (size_t)l * DMODEL * 3 * DMODEL, qkv_b + l * 3 * DMODEL,
            nullptr, qkvb, NTOK, 3 * DMODEL, DMODEL);
        kn_k<<<NTOK, 512, 0, stream>>>(qkvb, kn);
        attn_k<<<NTOK * NHEAD / 4, 256, 0, stream>>>(qkvb, kn, indices, distance, lam, xo, l);
        gemm_k<3><<<dim3(NTOK / BM, DMODEL / BN), blk, 0, stream>>>(
            xo, proj_w + (size_t)l * DMODEL * DMODEL, proj_b + l * DMODEL, h, h,
            NTOK, DMODEL, DMODEL);
        ln_k<<<NTOK, blk, 0, stream>>>(h, ln2_g + l * DMODEL, ln2_b + l * DMODEL, xa, 1e-5f);
        gemm_k<2><<<dim3(NTOK / BM, (4 * DMODEL) / BN), blk, 0, stream>>>(
            xa, fc1_w + (size_t)l * DMODEL * 4 * DMODEL, fc1_b + l * 4 * DMODEL,
            nullptr, fc1b, NTOK, 4 * DMODEL, DMODEL);
        gemm_k<3><<<dim3(NTOK / BM, DMODEL / BN), blk, 0, stream>>>(
            fc1b, fc2_w + (size_t)l * 4 * DMODEL * DMODEL, fc2_b + l * DMODEL, h, h,
            NTOK, DMODEL, 4 * DMODEL);
    }

    ln_k<<<NTOK, blk, 0, stream>>>(h, lnf_g, lnf_b, xa, 1e-6f);
    colpart_k<<<256, 512, 0, stream>>>(xa, part);
    finhead_k<<<1, 512, 0, stream>>>(part, head_w, head_b, out);
}

// Round 3
// 742.371 us; speedup vs baseline: 2.9903x; 1.8129x over previous
//
#include <hip/hip_runtime.h>
#include <hip/hip_bf16.h>

#define NTOK 4096
#define EMB 1024
#define DMODEL 512
#define NHEAD 8
#define NLAYER 2
#define NCLS 2
#define KMAX 160

typedef __attribute__((ext_vector_type(8))) short bf16x8;
typedef __attribute__((ext_vector_type(4))) float f32x4;

__device__ inline unsigned short f2b(float f) {
    unsigned u = __float_as_uint(f);
    u = u + 0x7FFFu + ((u >> 16) & 1u);
    return (unsigned short)(u >> 16);
}

__device__ inline float wsum(float v) {
    for (int o = 32; o > 0; o >>= 1) v += __shfl_xor(v, o, 64);
    return v;
}
__device__ inline float wmax(float v) {
    for (int o = 32; o > 0; o >>= 1) v = fmaxf(v, __shfl_xor(v, o, 64));
    return v;
}

// ---------------- weight convert+transpose: W[K][N] f32 -> Wt[N][K] bf16 ----------------
__global__ __launch_bounds__(256) void wcvt_k(const float* __restrict__ W,
                                              unsigned short* __restrict__ Wt,
                                              int K, int N)
{
    __shared__ unsigned short tile[64][72];
    int k0 = blockIdx.x * 64, n0 = blockIdx.y * 64;
    int t = threadIdx.x;
    int kl = t >> 2, nb = (t & 3) * 16;
    const float* src = W + (size_t)(k0 + kl) * N + n0 + nb;
#pragma unroll
    for (int i = 0; i < 4; i++) {
        float4 v = *(const float4*)(src + 4 * i);
        tile[nb + 4 * i + 0][kl] = f2b(v.x);
        tile[nb + 4 * i + 1][kl] = f2b(v.y);
        tile[nb + 4 * i + 2][kl] = f2b(v.z);
        tile[nb + 4 * i + 3][kl] = f2b(v.w);
    }
    __syncthreads();
    int nl = t >> 2, ks = (t & 3) * 16;
    unsigned short* dst = Wt + (size_t)(n0 + nl) * K + k0 + ks;
    *(uint4*)dst = *(const uint4*)&tile[nl][ks];
    *(uint4*)(dst + 8) = *(const uint4*)&tile[nl][ks + 8];
}

// ---------------- x f32 -> bf16 flat ----------------
__global__ __launch_bounds__(256) void xcvt_k(const float* __restrict__ X,
                                              unsigned short* __restrict__ Xb)
{
    int i = (blockIdx.x * 256 + threadIdx.x) * 8;
    float4 a = *(const float4*)(X + i);
    float4 b = *(const float4*)(X + i + 4);
    unsigned short o[8];
    o[0] = f2b(a.x); o[1] = f2b(a.y); o[2] = f2b(a.z); o[3] = f2b(a.w);
    o[4] = f2b(b.x); o[5] = f2b(b.y); o[6] = f2b(b.z); o[7] = f2b(b.w);
    *(uint4*)(Xb + i) = *(const uint4*)o;
}

// ---------------- MFMA GEMM: C = epilogue(A_bf16[M,K] @ Wt_bf16[N,K]^T + bias) -------
// MODE 0: Cf = v                      (qkv)
// MODE 1: Cf = resid + relu(v)        (res)
// MODE 2: Cb = bf16(gelu(v))          (fc1)
// MODE 3: Cf = resid + v              (proj, fc2; resid may alias Cf)
// MODE 4: Cf = v and Cb = bf16(v)     (adapter)
template <int MODE>
__global__ __launch_bounds__(256) void mgemm_k(
    const unsigned short* __restrict__ A, const unsigned short* __restrict__ Wt,
    const float* __restrict__ bias, const float* __restrict__ resid,
    float* __restrict__ Cf, unsigned short* __restrict__ Cb,
    int M, int N, int K)
{
    __shared__ unsigned short Asl[64 * 40];
    __shared__ unsigned short Bsl[128 * 40];
    int tid = threadIdx.x;
    int bm = blockIdx.x * 64, bn = blockIdx.y * 128;
    int lane = tid & 63, wid = tid >> 6;
    int wm = wid >> 1, wn = wid & 1;
    int l15 = lane & 15, l4 = lane >> 4;

    f32x4 acc[2][4] = {};

    int ar = tid >> 2, ak = (tid & 3) * 8;
    const unsigned short* Ap  = A  + (size_t)(bm + ar) * K + ak;
    const unsigned short* Bp0 = Wt + (size_t)(bn + ar) * K + ak;
    const unsigned short* Bp1 = Wt + (size_t)(bn + 64 + ar) * K + ak;

    int aoff  = ar * 40 + ak;
    int arow0 = (wm * 32 + l15) * 40 + l4 * 8;
    int brow0 = (wn * 64 + l15) * 40 + l4 * 8;

    for (int k0 = 0; k0 < K; k0 += 32) {
        uint4 av  = *(const uint4*)(Ap + k0);
        uint4 bv0 = *(const uint4*)(Bp0 + k0);
        uint4 bv1 = *(const uint4*)(Bp1 + k0);
        *(uint4*)&Asl[aoff] = av;
        *(uint4*)&Bsl[aoff] = bv0;
        *(uint4*)&Bsl[aoff + 64 * 40] = bv1;
        __syncthreads();
        bf16x8 af[2], bfr[4];
#pragma unroll
        for (int mr = 0; mr < 2; mr++) af[mr] = *(const bf16x8*)&Asl[arow0 + mr * 16 * 40];
#pragma unroll
        for (int nr = 0; nr < 4; nr++) bfr[nr] = *(const bf16x8*)&Bsl[brow0 + nr * 16 * 40];
#pragma unroll
        for (int mr = 0; mr < 2; mr++)
#pragma unroll
            for (int nr = 0; nr < 4; nr++)
                acc[mr][nr] = __builtin_amdgcn_mfma_f32_16x16x32_bf16(af[mr], bfr[nr], acc[mr][nr], 0, 0, 0);
        __syncthreads();
    }

#pragma unroll
    for (int mr = 0; mr < 2; mr++) {
#pragma unroll
        for (int nr = 0; nr < 4; nr++) {
            int col = bn + wn * 64 + nr * 16 + l15;
            float bcol = bias[col];
#pragma unroll
            for (int r = 0; r < 4; r++) {
                int row = bm + wm * 32 + mr * 16 + l4 * 4 + r;
                size_t off = (size_t)row * N + col;
                float v = acc[mr][nr][r] + bcol;
                if (MODE == 0) {
                    Cf[off] = v;
                } else if (MODE == 1) {
                    Cf[off] = resid[off] + fmaxf(v, 0.f);
                } else if (MODE == 2) {
                    float t3 = tanhf(0.7978845608028654f * (v + 0.044715f * v * v * v));
                    Cb[off] = f2b(0.5f * v * (1.f + t3));
                } else if (MODE == 3) {
                    Cf[off] = resid[off] + v;
                } else {
                    Cf[off] = v;
                    Cb[off] = f2b(v);
                }
            }
        }
    }
}

// ---------------- LayerNorm over D=512, one row per block ----------------
// OUTB=1: bf16 output, OUTB=0: f32 output
template <int OUTB>
__global__ __launch_bounds__(256) void ln_k(
    const float* __restrict__ X, const float* __restrict__ g,
    const float* __restrict__ bta, void* __restrict__ Yv, float eps)
{
    int row = blockIdx.x;
    int tid = threadIdx.x;
    const float* xr = X + (size_t)row * DMODEL;
    float v0 = xr[tid], v1 = xr[tid + 256];
    __shared__ float red[8];
    float s = wsum(v0 + v1);
    int wid = tid >> 6, lane = tid & 63;
    if (lane == 0) red[wid] = s;
    __syncthreads();
    float m = (red[0] + red[1] + red[2] + red[3]) * (1.f / DMODEL);
    float d0 = v0 - m, d1 = v1 - m;
    float sq = wsum(d0 * d0 + d1 * d1);
    if (lane == 0) red[4 + wid] = sq;
    __syncthreads();
    float var = (red[4] + red[5] + red[6] + red[7]) * (1.f / DMODEL);
    float rs = 1.0f / sqrtf(var + eps);
    float y0 = d0 * rs * g[tid] + bta[tid];
    float y1 = d1 * rs * g[tid + 256] + bta[tid + 256];
    if (OUTB) {
        unsigned short* Y = (unsigned short*)Yv;
        Y[(size_t)row * DMODEL + tid] = f2b(y0);
        Y[(size_t)row * DMODEL + tid + 256] = f2b(y1);
    } else {
        float* Y = (float*)Yv;
        Y[(size_t)row * DMODEL + tid] = y0;
        Y[(size_t)row * DMODEL + tid + 256] = y1;
    }
}

// ---------------- kn[n,h] = sum_d k[n,h,d]^2 ----------------
__global__ __launch_bounds__(512) void kn_k(const float* __restrict__ qkv, float* __restrict__ kn)
{
    int n = blockIdx.x;
    int hh = threadIdx.x >> 6, lane = threadIdx.x & 63;
    float kv = qkv[(size_t)n * 1536 + 512 + hh * 64 + lane];
    float ks = wsum(kv * kv);
    if (lane == 0) kn[n * NHEAD + hh] = ks;
}

// ---------------- gathered attention: one wave per (n, head), 4 waves/block --------
__global__ __launch_bounds__(256) void attn_k(
    const float* __restrict__ qkv, const float* __restrict__ kn,
    const int* __restrict__ indices, const float* __restrict__ distance,
    const float* __restrict__ lam, unsigned short* __restrict__ xo, int layer)
{
    int wid = threadIdx.x >> 6, lane = threadIdx.x & 63;
    int id = blockIdx.x * 4 + wid;
    int n = id >> 3, hh = id & 7;
    int Kh = 32 + 16 * hh + (hh == 7 ? 16 : 0);   // 32,48,64,80,96,112,128,160

    __shared__ __align__(16) float qs[4][64];
    __shared__ float asc[4][KMAX];
    __shared__ int   sidx[4][KMAX];

    const float* qrow = qkv + (size_t)n * 1536 + hh * 64;
    float qd = qrow[lane];
    qs[wid][lane] = qd;
    float qn2 = wsum(qd * qd);
    float sp = log1pf(expf(lam[layer * NHEAD + hh]));

    const int* irow = indices + (size_t)n * KMAX;
    const float* drow = distance + (size_t)n * NTOK;

    // ---- Phase A: scores, lane kk = j*64 + lane ----
    float sc[3];
    int   sid[3];
#pragma unroll
    for (int j = 0; j < 3; j++) { sc[j] = -1e30f; sid[j] = 0; }

    const float4* q4 = (const float4*)&qs[wid][0];
#pragma unroll
    for (int j = 0; j < 3; j++) {
        if (j * 64 >= Kh) break;            // wave-uniform
        int kk = j * 64 + lane;
        bool ok = kk < Kh;
        int idx = ok ? irow[kk] : 0;
        sid[j] = idx;
        const float4* krow = (const float4*)(qkv + (size_t)idx * 1536 + 512 + hh * 64);
        float dot = 0.f;
#pragma unroll
        for (int d = 0; d < 16; d++) {
            float4 kv = krow[d];
            float4 qv = q4[d];
            dot += qv.x * kv.x + qv.y * kv.y + qv.z * kv.z + qv.w * kv.w;
        }
        float knv = kn[idx * NHEAD + hh];
        float dist = drow[idx];
        float dec = expf(-sp * dist) + 1e-6f;
        float s = (dot - 0.5f * (qn2 + knv)) * 0.125f + logf(dec);
        sc[j] = ok ? s : -1e30f;
    }

    // ---- Phase B: softmax in registers ----
    float mx = fmaxf(fmaxf(sc[0], sc[1]), sc[2]);
    mx = wmax(mx);
    float se = 0.f;
#pragma unroll
    for (int j = 0; j < 3; j++) {
        float e = (sc[j] > -1e29f) ? expf(sc[j] - mx) : 0.f;
        sc[j] = e;
        se += e;
    }
    se = wsum(se);
    float inv = 1.f / se;

#pragma unroll
    for (int j = 0; j < 3; j++) {
        int kk = j * 64 + lane;
        if (kk < Kh) {
            asc[wid][kk] = sc[j] * inv;
            sidx[wid][kk] = sid[j];
        }
    }

    // ---- Phase C: PV, lane = d, 8-deep pipelined ----
    float acc = 0.f;
    const float* vbase = qkv + 1024 + hh * 64 + lane;
    for (int k0 = 0; k0 < Kh; k0 += 8) {
        float vv[8], aa[8];
        int ii[8];
#pragma unroll
        for (int u = 0; u < 8; u++) { ii[u] = sidx[wid][k0 + u]; aa[u] = asc[wid][k0 + u]; }
#pragma unroll
        for (int u = 0; u < 8; u++) vv[u] = vbase[(size_t)ii[u] * 1536];
#pragma unroll
        for (int u = 0; u < 8; u++) acc += aa[u] * vv[u];
    }
    xo[(size_t)n * DMODEL + hh * 64 + lane] = f2b(acc);
}

// ---------------- column partial sums of Y (4096 x 512): 16 rows per block ----------------
__global__ __launch_bounds__(512) void colpart_k(const float* __restrict__ Y, float* __restrict__ part)
{
    int c = threadIdx.x;
    int blk = blockIdx.x;
    const float* p = Y + (size_t)blk * 16 * DMODEL + c;
    float s = 0.f;
#pragma unroll
    for (int r = 0; r < 16; r++) s += p[r * DMODEL];
    part[blk * DMODEL + c] = s;
}

// ---------------- finish mean + head GEMV ----------------
__global__ __launch_bounds__(512) void finhead_k(
    const float* __restrict__ part, const float* __restrict__ head_w,
    const float* __restrict__ head_b, float* __restrict__ out)
{
    __shared__ float mv[DMODEL];
    int c = threadIdx.x;
    float s = 0.f;
    for (int i = 0; i < 256; i++) s += part[i * DMODEL + c];
    mv[c] = s * (1.f / NTOK);
    __syncthreads();
    if (c < 64) {
        float a0 = 0.f, a1 = 0.f;
        for (int d = c; d < DMODEL; d += 64) {
            float m = mv[d];
            a0 += m * head_w[d * NCLS + 0];
            a1 += m * head_w[d * NCLS + 1];
        }
        a0 = wsum(a0);
        a1 = wsum(a1);
        if (c == 0) { out[0] = a0 + head_b[0]; out[1] = a1 + head_b[1]; }
    }
}

extern "C" void kernel_launch(void* const* d_in, const int* in_sizes, int n_in,
                              void* d_out, int out_size, void* d_ws, size_t ws_size,
                              hipStream_t stream)
{
    const float* x        = (const float*)d_in[0];
    const float* distance = (const float*)d_in[1];
    const int*   indices  = (const int*)d_in[2];
    const float* adapter_w = (const float*)d_in[5];
    const float* adapter_b = (const float*)d_in[6];
    const float* res_w     = (const float*)d_in[7];
    const float* res_b     = (const float*)d_in[8];
    const float* ln1_g     = (const float*)d_in[9];
    const float* ln1_b     = (const float*)d_in[10];
    const float* qkv_w     = (const float*)d_in[11];
    const float* qkv_b     = (const float*)d_in[12];
    const float* proj_w    = (const float*)d_in[13];
    const float* proj_b    = (const float*)d_in[14];
    const float* ln2_g     = (const float*)d_in[15];
    const float* ln2_b     = (const float*)d_in[16];
    const float* fc1_w     = (const float*)d_in[17];
    const float* fc1_b     = (const float*)d_in[18];
    const float* fc2_w     = (const float*)d_in[19];
    const float* fc2_b     = (const float*)d_in[20];
    const float* lam       = (const float*)d_in[21];
    const float* lnf_g     = (const float*)d_in[22];
    const float* lnf_b     = (const float*)d_in[23];
    const float* head_w    = (const float*)d_in[24];
    const float* head_b    = (const float*)d_in[25];
    float* out = (float*)d_out;

    char* wsb = (char*)d_ws;
    // layout (bytes)
    float* h   = (float*)(wsb);                         // 8 MB
    float* h0  = (float*)(wsb + (8u << 20));            // 8 MB (later: lnf out)
    char* shared = wsb + (16u << 20);                   // 24 MB shared region
    unsigned short* xb   = (unsigned short*)shared;                 // 8 MB
    float*          qkvb = (float*)shared;                          // 24 MB
    unsigned short* fc1b = (unsigned short*)shared;                 // 16 MB
    unsigned short* adapter_wt = (unsigned short*)(shared + (8u << 20));  // 1 MB (dead after res)
    unsigned short* res_wt     = (unsigned short*)(shared + (9u << 20));  // 0.5 MB
    unsigned short* lnb  = (unsigned short*)(wsb + (40u << 20));    // 4 MB (also h0b)
    unsigned short* h0b  = lnb;
    unsigned short* xob  = (unsigned short*)(wsb + (44u << 20));    // 4 MB
    unsigned short* qkv_wt = (unsigned short*)(wsb + (48u << 20));  // 3 MB
    unsigned short* proj_wt = (unsigned short*)(wsb + (51u << 20)); // 1 MB
    unsigned short* fc1_wt  = (unsigned short*)(wsb + (52u << 20)); // 4 MB
    unsigned short* fc2_wt  = (unsigned short*)(wsb + (56u << 20)); // 4 MB
    float* kn   = (float*)(wsb + (60u << 20));                      // 128 KB
    float* part = (float*)(wsb + (60u << 20) + (1u << 18));         // 512 KB

    dim3 blk(256);

    // --- weight conversions (every launch; deterministic) ---
    xcvt_k<<<(NTOK * EMB) / 2048, blk, 0, stream>>>(x, xb);
    wcvt_k<<<dim3(EMB / 64, DMODEL / 64), blk, 0, stream>>>(adapter_w, adapter_wt, EMB, DMODEL);
    wcvt_k<<<dim3(DMODEL / 64, DMODEL / 64), blk, 0, stream>>>(res_w, res_wt, DMODEL, DMODEL);
    for (int l = 0; l < NLAYER; l++) {
        wcvt_k<<<dim3(DMODEL / 64, 1536 / 64), blk, 0, stream>>>(
            qkv_w + (size_t)l * DMODEL * 1536, qkv_wt + (size_t)l * 1536 * DMODEL, DMODEL, 1536);
        wcvt_k<<<dim3(DMODEL / 64, DMODEL / 64), blk, 0, stream>>>(
            proj_w + (size_t)l * DMODEL * DMODEL, proj_wt + (size_t)l * DMODEL * DMODEL, DMODEL, DMODEL);
        wcvt_k<<<dim3(DMODEL / 64, 2048 / 64), blk, 0, stream>>>(
            fc1_w + (size_t)l * DMODEL * 2048, fc1_wt + (size_t)l * 2048 * DMODEL, DMODEL, 2048);
        wcvt_k<<<dim3(2048 / 64, DMODEL / 64), blk, 0, stream>>>(
            fc2_w + (size_t)l * 2048 * DMODEL, fc2_wt + (size_t)l * DMODEL * 2048, 2048, DMODEL);
    }

    // --- adapter: h0 = x @ adapter_w + b (f32 + bf16 copies) ---
    mgemm_k<4><<<dim3(NTOK / 64, DMODEL / 128), blk, 0, stream>>>(
        xb, adapter_wt, adapter_b, nullptr, h0, h0b, NTOK, DMODEL, EMB);
    // --- h = h0 + relu(h0 @ res_w + b) ---
    mgemm_k<1><<<dim3(NTOK / 64, DMODEL / 128), blk, 0, stream>>>(
        h0b, res_wt, res_b, h0, h, nullptr, NTOK, DMODEL, DMODEL);

    for (int l = 0; l < NLAYER; l++) {
        ln_k<1><<<NTOK, blk, 0, stream>>>(h, ln1_g + l * DMODEL, ln1_b + l * DMODEL, lnb, 1e-5f);
        mgemm_k<0><<<dim3(NTOK / 64, 1536 / 128), blk, 0, stream>>>(
            lnb, qkv_wt + (size_t)l * 1536 * DMODEL, qkv_b + l * 1536, nullptr,
            qkvb, nullptr, NTOK, 1536, DMODEL);
        kn_k<<<NTOK, 512, 0, stream>>>(qkvb, kn);
        attn_k<<<NTOK * NHEAD / 4, blk, 0, stream>>>(qkvb, kn, indices, distance, lam, xob, l);
        mgemm_k<3><<<dim3(NTOK / 64, DMODEL / 128), blk, 0, stream>>>(
            xob, proj_wt + (size_t)l * DMODEL * DMODEL, proj_b + l * DMODEL, h,
            h, nullptr, NTOK, DMODEL, DMODEL);
        ln_k<1><<<NTOK, blk, 0, stream>>>(h, ln2_g + l * DMODEL, ln2_b + l * DMODEL, lnb, 1e-5f);
        mgemm_k<2><<<dim3(NTOK / 64, 2048 / 128), blk, 0, stream>>>(
            lnb, fc1_wt + (size_t)l * 2048 * DMODEL, fc1_b + l * 2048, nullptr,
            nullptr, fc1b, NTOK, 2048, DMODEL);
        mgemm_k<3><<<dim3(NTOK / 64, DMODEL / 128), blk, 0, stream>>>(
            fc1b, fc2_wt + (size_t)l * DMODEL * 2048, fc2_b + l * DMODEL, h,
            h, nullptr, NTOK, DMODEL, 2048);
    }

    ln_k<0><<<NTOK, blk, 0, stream>>>(h, lnf_g, lnf_b, h0, 1e-6f);
    colpart_k<<<256, 512, 0, stream>>>(h0, part);
    finhead_k<<<1, 512, 0, stream>>>(part, head_w, head_b, out);
}

// Round 4
// 575.622 us; speedup vs baseline: 3.8565x; 1.2897x over previous
//
#include <hip/hip_runtime.h>
#include <hip/hip_bf16.h>

#define NTOK 4096
#define EMB 1024
#define DMODEL 512
#define NHEAD 8
#define NLAYER 2
#define NCLS 2
#define KMAX 160

typedef __attribute__((ext_vector_type(8))) short bf16x8;
typedef __attribute__((ext_vector_type(4))) float f32x4;

__device__ inline unsigned short f2b(float f) {
    unsigned u = __float_as_uint(f);
    u = u + 0x7FFFu + ((u >> 16) & 1u);
    return (unsigned short)(u >> 16);
}
__device__ inline float b2f(unsigned short s) {
    return __uint_as_float((unsigned)s << 16);
}

__device__ inline float wsum(float v) {
    for (int o = 32; o > 0; o >>= 1) v += __shfl_xor(v, o, 64);
    return v;
}
__device__ inline float wmax(float v) {
    for (int o = 32; o > 0; o >>= 1) v = fmaxf(v, __shfl_xor(v, o, 64));
    return v;
}

// ---------------- weight convert+transpose: W[K][N] f32 -> Wt[N][K] bf16 ----------------
__global__ __launch_bounds__(256) void wcvt_k(const float* __restrict__ W,
                                              unsigned short* __restrict__ Wt,
                                              int K, int N)
{
    __shared__ unsigned short tile[64][72];
    int k0 = blockIdx.x * 64, n0 = blockIdx.y * 64;
    int t = threadIdx.x;
    int kl = t >> 2, nb = (t & 3) * 16;
    const float* src = W + (size_t)(k0 + kl) * N + n0 + nb;
#pragma unroll
    for (int i = 0; i < 4; i++) {
        float4 v = *(const float4*)(src + 4 * i);
        tile[nb + 4 * i + 0][kl] = f2b(v.x);
        tile[nb + 4 * i + 1][kl] = f2b(v.y);
        tile[nb + 4 * i + 2][kl] = f2b(v.z);
        tile[nb + 4 * i + 3][kl] = f2b(v.w);
    }
    __syncthreads();
    int nl = t >> 2, ks = (t & 3) * 16;
    unsigned short* dst = Wt + (size_t)(n0 + nl) * K + k0 + ks;
    *(uint4*)dst = *(const uint4*)&tile[nl][ks];
    *(uint4*)(dst + 8) = *(const uint4*)&tile[nl][ks + 8];
}

// ---------------- x f32 -> bf16 flat ----------------
__global__ __launch_bounds__(256) void xcvt_k(const float* __restrict__ X,
                                              unsigned short* __restrict__ Xb)
{
    int i = (blockIdx.x * 256 + threadIdx.x) * 8;
    float4 a = *(const float4*)(X + i);
    float4 b = *(const float4*)(X + i + 4);
    unsigned short o[8];
    o[0] = f2b(a.x); o[1] = f2b(a.y); o[2] = f2b(a.z); o[3] = f2b(a.w);
    o[4] = f2b(b.x); o[5] = f2b(b.y); o[6] = f2b(b.z); o[7] = f2b(b.w);
    *(uint4*)(Xb + i) = *(const uint4*)o;
}

// ---------------- dsel[n][k] = distance[n][indices[n][k]] (layer/head independent) ----
__global__ __launch_bounds__(256) void dsel_k(const float* __restrict__ distance,
                                              const int* __restrict__ indices,
                                              float* __restrict__ dsel)
{
    int n = blockIdx.x, t = threadIdx.x;
    if (t < KMAX) {
        int idx = indices[(size_t)n * KMAX + t];
        dsel[(size_t)n * KMAX + t] = distance[(size_t)n * NTOK + idx];
    }
}

// ---------------- MFMA GEMM: C = epilogue(A_bf16[M,K] @ Wt_bf16[N,K]^T + bias) -------
// MODE 0: Cf = v
// MODE 1: Cf = resid + relu(v)        (res)
// MODE 2: Cb = bf16(gelu(v))          (fc1)
// MODE 3: Cf = resid + v              (proj, fc2; resid may alias Cf)
// MODE 4: Cf = v and Cb = bf16(v)     (adapter)
// MODE 5: Cb = bf16(v)                (qkv)
template <int MODE>
__global__ __launch_bounds__(256) void mgemm_k(
    const unsigned short* __restrict__ A, const unsigned short* __restrict__ Wt,
    const float* __restrict__ bias, const float* __restrict__ resid,
    float* __restrict__ Cf, unsigned short* __restrict__ Cb,
    int M, int N, int K)
{
    __shared__ unsigned short Asl[64 * 40];
    __shared__ unsigned short Bsl[128 * 40];
    int tid = threadIdx.x;
    int bm = blockIdx.x * 64, bn = blockIdx.y * 128;
    int lane = tid & 63, wid = tid >> 6;
    int wm = wid >> 1, wn = wid & 1;
    int l15 = lane & 15, l4 = lane >> 4;

    f32x4 acc[2][4] = {};

    int ar = tid >> 2, ak = (tid & 3) * 8;
    const unsigned short* Ap  = A  + (size_t)(bm + ar) * K + ak;
    const unsigned short* Bp0 = Wt + (size_t)(bn + ar) * K + ak;
    const unsigned short* Bp1 = Wt + (size_t)(bn + 64 + ar) * K + ak;

    int aoff  = ar * 40 + ak;
    int arow0 = (wm * 32 + l15) * 40 + l4 * 8;
    int brow0 = (wn * 64 + l15) * 40 + l4 * 8;

    for (int k0 = 0; k0 < K; k0 += 32) {
        uint4 av  = *(const uint4*)(Ap + k0);
        uint4 bv0 = *(const uint4*)(Bp0 + k0);
        uint4 bv1 = *(const uint4*)(Bp1 + k0);
        *(uint4*)&Asl[aoff] = av;
        *(uint4*)&Bsl[aoff] = bv0;
        *(uint4*)&Bsl[aoff + 64 * 40] = bv1;
        __syncthreads();
        bf16x8 af[2], bfr[4];
#pragma unroll
        for (int mr = 0; mr < 2; mr++) af[mr] = *(const bf16x8*)&Asl[arow0 + mr * 16 * 40];
#pragma unroll
        for (int nr = 0; nr < 4; nr++) bfr[nr] = *(const bf16x8*)&Bsl[brow0 + nr * 16 * 40];
#pragma unroll
        for (int mr = 0; mr < 2; mr++)
#pragma unroll
            for (int nr = 0; nr < 4; nr++)
                acc[mr][nr] = __builtin_amdgcn_mfma_f32_16x16x32_bf16(af[mr], bfr[nr], acc[mr][nr], 0, 0, 0);
        __syncthreads();
    }

#pragma unroll
    for (int mr = 0; mr < 2; mr++) {
#pragma unroll
        for (int nr = 0; nr < 4; nr++) {
            int col = bn + wn * 64 + nr * 16 + l15;
            float bcol = bias[col];
#pragma unroll
            for (int r = 0; r < 4; r++) {
                int row = bm + wm * 32 + mr * 16 + l4 * 4 + r;
                size_t off = (size_t)row * N + col;
                float v = acc[mr][nr][r] + bcol;
                if (MODE == 0) {
                    Cf[off] = v;
                } else if (MODE == 1) {
                    Cf[off] = resid[off] + fmaxf(v, 0.f);
                } else if (MODE == 2) {
                    float t3 = tanhf(0.7978845608028654f * (v + 0.044715f * v * v * v));
                    Cb[off] = f2b(0.5f * v * (1.f + t3));
                } else if (MODE == 3) {
                    Cf[off] = resid[off] + v;
                } else if (MODE == 4) {
                    Cf[off] = v;
                    Cb[off] = f2b(v);
                } else {
                    Cb[off] = f2b(v);
                }
            }
        }
    }
}

// ---------------- LayerNorm over D=512, one row per block ----------------
template <int OUTB>
__global__ __launch_bounds__(256) void ln_k(
    const float* __restrict__ X, const float* __restrict__ g,
    const float* __restrict__ bta, void* __restrict__ Yv, float eps)
{
    int row = blockIdx.x;
    int tid = threadIdx.x;
    const float* xr = X + (size_t)row * DMODEL;
    float v0 = xr[tid], v1 = xr[tid + 256];
    __shared__ float red[8];
    float s = wsum(v0 + v1);
    int wid = tid >> 6, lane = tid & 63;
    if (lane == 0) red[wid] = s;
    __syncthreads();
    float m = (red[0] + red[1] + red[2] + red[3]) * (1.f / DMODEL);
    float d0 = v0 - m, d1 = v1 - m;
    float sq = wsum(d0 * d0 + d1 * d1);
    if (lane == 0) red[4 + wid] = sq;
    __syncthreads();
    float var = (red[4] + red[5] + red[6] + red[7]) * (1.f / DMODEL);
    float rs = 1.0f / sqrtf(var + eps);
    float y0 = d0 * rs * g[tid] + bta[tid];
    float y1 = d1 * rs * g[tid + 256] + bta[tid + 256];
    if (OUTB) {
        unsigned short* Y = (unsigned short*)Yv;
        Y[(size_t)row * DMODEL + tid] = f2b(y0);
        Y[(size_t)row * DMODEL + tid + 256] = f2b(y1);
    } else {
        float* Y = (float*)Yv;
        Y[(size_t)row * DMODEL + tid] = y0;
        Y[(size_t)row * DMODEL + tid + 256] = y1;
    }
}

// ---------------- gathered attention, bf16 qkv, head->XCD pinned ----------------
// Work table (assumes round-robin blockIdx%8 -> XCD): per-XCD loads
// {h7a:80, h7b:80, h6a:64, h6b:64, h5:112, h4:96, h3+h0:112, h2+h1:112}
__global__ __launch_bounds__(256) void attn_k(
    const unsigned short* __restrict__ qkv,   // [n][1536] bf16
    const int* __restrict__ indices, const float* __restrict__ dsel,
    const float* __restrict__ lam, unsigned short* __restrict__ xo, int layer)
{
    const int h_a[8]   = {7, 7, 6, 6, 5, 4, 3, 2};
    const int lim_a[8] = {512, 512, 512, 512, 1024, 1024, 1024, 1024};
    const int off_a[8] = {0, 2048, 0, 2048, 0, 0, 0, 0};
    const int h_b[8]   = {-1, -1, -1, -1, -1, -1, 0, 1};

    int xcd = blockIdx.x & 7;
    int t = blockIdx.x >> 3;
    int hh, nb;
    if (t < lim_a[xcd]) {
        hh = h_a[xcd]; nb = off_a[xcd] + t * 4;
    } else if (h_b[xcd] >= 0 && t < lim_a[xcd] + 1024) {
        hh = h_b[xcd]; nb = (t - lim_a[xcd]) * 4;
    } else {
        return;
    }
    int wid = threadIdx.x >> 6, lane = threadIdx.x & 63;
    int n = nb + wid;
    int Kh = 32 + 16 * hh + (hh == 7 ? 16 : 0);   // 32,48,64,80,96,112,128,160

    __shared__ __align__(16) float qs[4][64];
    __shared__ float asc[4][KMAX];
    __shared__ int   sidx[4][KMAX];

    float qd = b2f(qkv[(size_t)n * 1536 + hh * 64 + lane]);
    qs[wid][lane] = qd;
    float qn2 = wsum(qd * qd);
    float sp = log1pf(expf(lam[layer * NHEAD + hh]));

    const int* irow = indices + (size_t)n * KMAX;
    const float* drow = dsel + (size_t)n * KMAX;

    // ---- Phase A: scores + kn self-dot, lane = neighbor ----
    float sc[3];
    int   sid[3];
#pragma unroll
    for (int j = 0; j < 3; j++) { sc[j] = -1e30f; sid[j] = 0; }

    const float4* q4 = (const float4*)&qs[wid][0];
#pragma unroll
    for (int j = 0; j < 3; j++) {
        if (j * 64 >= Kh) break;            // wave-uniform
        int kk = j * 64 + lane;
        bool ok = kk < Kh;
        int idx = ok ? irow[kk] : 0;
        sid[j] = idx;
        const uint4* krow = (const uint4*)(qkv + (size_t)idx * 1536 + 512 + hh * 64);
        float dot = 0.f, knl = 0.f;
#pragma unroll
        for (int c = 0; c < 8; c++) {
            uint4 kv = krow[c];
            const unsigned short* kp = (const unsigned short*)&kv;
            float4 qa = q4[c * 2], qb = q4[c * 2 + 1];
            float k0 = b2f(kp[0]), k1 = b2f(kp[1]), k2 = b2f(kp[2]), k3 = b2f(kp[3]);
            float k4 = b2f(kp[4]), k5 = b2f(kp[5]), k6 = b2f(kp[6]), k7 = b2f(kp[7]);
            dot += qa.x * k0 + qa.y * k1 + qa.z * k2 + qa.w * k3
                 + qb.x * k4 + qb.y * k5 + qb.z * k6 + qb.w * k7;
            knl += k0 * k0 + k1 * k1 + k2 * k2 + k3 * k3
                 + k4 * k4 + k5 * k5 + k6 * k6 + k7 * k7;
        }
        float dd = drow[ok ? kk : 0];
        float dec = expf(-sp * dd) + 1e-6f;
        float s = (dot - 0.5f * (qn2 + knl)) * 0.125f + logf(dec);
        sc[j] = ok ? s : -1e30f;
    }

    // ---- Phase B: softmax in registers ----
    float mx = fmaxf(fmaxf(sc[0], sc[1]), sc[2]);
    mx = wmax(mx);
    float se = 0.f;
#pragma unroll
    for (int j = 0; j < 3; j++) {
        float e = (sc[j] > -1e29f) ? expf(sc[j] - mx) : 0.f;
        sc[j] = e;
        se += e;
    }
    se = wsum(se);
    float inv = 1.f / se;

#pragma unroll
    for (int j = 0; j < 3; j++) {
        int kk = j * 64 + lane;
        if (kk < Kh) {
            asc[wid][kk] = sc[j] * inv;
            sidx[wid][kk] = sid[j];
        }
    }

    // ---- Phase C: PV, lane = d, 8-deep pipelined ----
    float acc = 0.f;
    const unsigned short* vbase = qkv + 1024 + hh * 64 + lane;
    for (int k0 = 0; k0 < Kh; k0 += 8) {
        float aa[8];
        unsigned short vv[8];
        int ii[8];
#pragma unroll
        for (int u = 0; u < 8; u++) { ii[u] = sidx[wid][k0 + u]; aa[u] = asc[wid][k0 + u]; }
#pragma unroll
        for (int u = 0; u < 8; u++) vv[u] = vbase[(size_t)ii[u] * 1536];
#pragma unroll
        for (int u = 0; u < 8; u++) acc += aa[u] * b2f(vv[u]);
    }
    xo[(size_t)n * DMODEL + hh * 64 + lane] = f2b(acc);
}

// ---------------- column partial sums of Y (4096 x 512): 16 rows per block ----------------
__global__ __launch_bounds__(512) void colpart_k(const float* __restrict__ Y, float* __restrict__ part)
{
    int c = threadIdx.x;
    int blk = blockIdx.x;
    const float* p = Y + (size_t)blk * 16 * DMODEL + c;
    float s = 0.f;
#pragma unroll
    for (int r = 0; r < 16; r++) s += p[r * DMODEL];
    part[blk * DMODEL + c] = s;
}

// ---------------- finish mean + head GEMV ----------------
__global__ __launch_bounds__(512) void finhead_k(
    const float* __restrict__ part, const float* __restrict__ head_w,
    const float* __restrict__ head_b, float* __restrict__ out)
{
    __shared__ float mv[DMODEL];
    int c = threadIdx.x;
    float s = 0.f;
    for (int i = 0; i < 256; i++) s += part[i * DMODEL + c];
    mv[c] = s * (1.f / NTOK);
    __syncthreads();
    if (c < 64) {
        float a0 = 0.f, a1 = 0.f;
        for (int d = c; d < DMODEL; d += 64) {
            float m = mv[d];
            a0 += m * head_w[d * NCLS + 0];
            a1 += m * head_w[d * NCLS + 1];
        }
        a0 = wsum(a0);
        a1 = wsum(a1);
        if (c == 0) { out[0] = a0 + head_b[0]; out[1] = a1 + head_b[1]; }
    }
}

extern "C" void kernel_launch(void* const* d_in, const int* in_sizes, int n_in,
                              void* d_out, int out_size, void* d_ws, size_t ws_size,
                              hipStream_t stream)
{
    const float* x        = (const float*)d_in[0];
    const float* distance = (const float*)d_in[1];
    const int*   indices  = (const int*)d_in[2];
    const float* adapter_w = (const float*)d_in[5];
    const float* adapter_b = (const float*)d_in[6];
    const float* res_w     = (const float*)d_in[7];
    const float* res_b     = (const float*)d_in[8];
    const float* ln1_g     = (const float*)d_in[9];
    const float* ln1_b     = (const float*)d_in[10];
    const float* qkv_w     = (const float*)d_in[11];
    const float* qkv_b     = (const float*)d_in[12];
    const float* proj_w    = (const float*)d_in[13];
    const float* proj_b    = (const float*)d_in[14];
    const float* ln2_g     = (const float*)d_in[15];
    const float* ln2_b     = (const float*)d_in[16];
    const float* fc1_w     = (const float*)d_in[17];
    const float* fc1_b     = (const float*)d_in[18];
    const float* fc2_w     = (const float*)d_in[19];
    const float* fc2_b     = (const float*)d_in[20];
    const float* lam       = (const float*)d_in[21];
    const float* lnf_g     = (const float*)d_in[22];
    const float* lnf_b     = (const float*)d_in[23];
    const float* head_w    = (const float*)d_in[24];
    const float* head_b    = (const float*)d_in[25];
    float* out = (float*)d_out;

    char* wsb = (char*)d_ws;
    // layout (bytes)
    float* h   = (float*)(wsb);                         // 8 MB
    float* h0  = (float*)(wsb + (8u << 20));            // 8 MB; dead during layers -> dsel
    float* dsel = (float*)(wsb + (8u << 20));           // 2.6 MB (after res, before lnf)
    char* shared = wsb + (16u << 20);                   // 24 MB shared region
    unsigned short* xb    = (unsigned short*)shared;                // 8 MB (dead after adapter)
    unsigned short* qkvbb = (unsigned short*)shared;                // 12 MB bf16 (qkv out, attn in)
    unsigned short* fc1b  = (unsigned short*)shared;                // 16 MB (after attn)
    unsigned short* adapter_wt = (unsigned short*)(shared + (8u << 20));  // 1 MB
    unsigned short* res_wt     = (unsigned short*)(shared + (9u << 20));  // 0.5 MB
    unsigned short* lnb  = (unsigned short*)(wsb + (40u << 20));    // 4 MB (also h0b)
    unsigned short* h0b  = lnb;
    unsigned short* xob  = (unsigned short*)(wsb + (44u << 20));    // 4 MB
    unsigned short* qkv_wt = (unsigned short*)(wsb + (48u << 20));  // 3 MB
    unsigned short* proj_wt = (unsigned short*)(wsb + (51u << 20)); // 1 MB
    unsigned short* fc1_wt  = (unsigned short*)(wsb + (52u << 20)); // 4 MB
    unsigned short* fc2_wt  = (unsigned short*)(wsb + (56u << 20)); // 4 MB
    float* part = (float*)(wsb + (60u << 20));                      // 512 KB

    dim3 blk(256);

    // --- conversions ---
    xcvt_k<<<(NTOK * EMB) / 2048, blk, 0, stream>>>(x, xb);
    wcvt_k<<<dim3(EMB / 64, DMODEL / 64), blk, 0, stream>>>(adapter_w, adapter_wt, EMB, DMODEL);
    wcvt_k<<<dim3(DMODEL / 64, DMODEL / 64), blk, 0, stream>>>(res_w, res_wt, DMODEL, DMODEL);
    for (int l = 0; l < NLAYER; l++) {
        wcvt_k<<<dim3(DMODEL / 64, 1536 / 64), blk, 0, stream>>>(
            qkv_w + (size_t)l * DMODEL * 1536, qkv_wt + (size_t)l * 1536 * DMODEL, DMODEL, 1536);
        wcvt_k<<<dim3(DMODEL / 64, DMODEL / 64), blk, 0, stream>>>(
            proj_w + (size_t)l * DMODEL * DMODEL, proj_wt + (size_t)l * DMODEL * DMODEL, DMODEL, DMODEL);
        wcvt_k<<<dim3(DMODEL / 64, 2048 / 64), blk, 0, stream>>>(
            fc1_w + (size_t)l * DMODEL * 2048, fc1_wt + (size_t)l * 2048 * DMODEL, DMODEL, 2048);
        wcvt_k<<<dim3(2048 / 64, DMODEL / 64), blk, 0, stream>>>(
            fc2_w + (size_t)l * 2048 * DMODEL, fc2_wt + (size_t)l * DMODEL * 2048, 2048, DMODEL);
    }

    // --- adapter: h0 = x @ adapter_w + b ---
    mgemm_k<4><<<dim3(NTOK / 64, DMODEL / 128), blk, 0, stream>>>(
        xb, adapter_wt, adapter_b, nullptr, h0, h0b, NTOK, DMODEL, EMB);
    // --- h = h0 + relu(h0 @ res_w + b) ---
    mgemm_k<1><<<dim3(NTOK / 64, DMODEL / 128), blk, 0, stream>>>(
        h0b, res_wt, res_b, h0, h, nullptr, NTOK, DMODEL, DMODEL);

    // dsel: h0 now dead until lnf
    dsel_k<<<NTOK, blk, 0, stream>>>(distance, indices, dsel);

    for (int l = 0; l < NLAYER; l++) {
        ln_k<1><<<NTOK, blk, 0, stream>>>(h, ln1_g + l * DMODEL, ln1_b + l * DMODEL, lnb, 1e-5f);
        mgemm_k<5><<<dim3(NTOK / 64, 1536 / 128), blk, 0, stream>>>(
            lnb, qkv_wt + (size_t)l * 1536 * DMODEL, qkv_b + l * 1536, nullptr,
            nullptr, qkvbb, NTOK, 1536, DMODEL);
        attn_k<<<16384, blk, 0, stream>>>(qkvbb, indices, dsel, lam, xob, l);
        mgemm_k<3><<<dim3(NTOK / 64, DMODEL / 128), blk, 0, stream>>>(
            xob, proj_wt + (size_t)l * DMODEL * DMODEL, proj_b + l * DMODEL, h,
            h, nullptr, NTOK, DMODEL, DMODEL);
        ln_k<1><<<NTOK, blk, 0, stream>>>(h, ln2_g + l * DMODEL, ln2_b + l * DMODEL, lnb, 1e-5f);
        mgemm_k<2><<<dim3(NTOK / 64, 2048 / 128), blk, 0, stream>>>(
            lnb, fc1_wt + (size_t)l * 2048 * DMODEL, fc1_b + l * 2048, nullptr,
            nullptr, fc1b, NTOK, 2048, DMODEL);
        mgemm_k<3><<<dim3(NTOK / 64, DMODEL / 128), blk, 0, stream>>>(
            fc1b, fc2_wt + (size_t)l * DMODEL * 2048, fc2_b + l * DMODEL, h,
            h, nullptr, NTOK, DMODEL, 2048);
    }

    ln_k<0><<<NTOK, blk, 0, stream>>>(h, lnf_g, lnf_b, h0, 1e-6f);
    colpart_k<<<256, 512, 0, stream>>>(h0, part);
    finhead_k<<<1, 512, 0, stream>>>(part, head_w, head_b, out);
}

// Round 5
// 484.444 us; speedup vs baseline: 4.5823x; 1.1882x over previous
//
#include <hip/hip_runtime.h>
#include <hip/hip_bf16.h>

#define NTOK 4096
#define EMB 1024
#define DMODEL 512
#define NHEAD 8
#define NLAYER 2
#define NCLS 2
#define KMAX 160

typedef __attribute__((ext_vector_type(8))) short bf16x8;
typedef __attribute__((ext_vector_type(4))) float f32x4;

__device__ inline unsigned short f2b(float f) {
    unsigned u = __float_as_uint(f);
    u = u + 0x7FFFu + ((u >> 16) & 1u);
    return (unsigned short)(u >> 16);
}
__device__ inline float b2f(unsigned short s) {
    return __uint_as_float((unsigned)s << 16);
}

__device__ inline float wsum(float v) {
    for (int o = 32; o > 0; o >>= 1) v += __shfl_xor(v, o, 64);
    return v;
}
__device__ inline float wmax(float v) {
    for (int o = 32; o > 0; o >>= 1) v = fmaxf(v, __shfl_xor(v, o, 64));
    return v;
}

// Balanced head->XCD schedule: work blocks of 4 rows, 1024 blocks/head.
// Per-XCD units (Kh*4/block): 368640,368640,368640,368960,368576,368640,368640,368384
__device__ const int g_s0cnt[8]  = {576, 448, 720, 144, 365, 490, 460, 159};
__device__ const int g_s0h[8]    = {7, 7, 6, 6, 5, 4, 3, 2};
__device__ const int g_s0base[8] = {0, 576, 160, 880, 659, 534, 564, 865};
__device__ const int g_s1cnt[8]  = {0, 160, 0, 659, 534, 564, 865, 1024};
__device__ const int g_s1h[8]    = {0, 6, 0, 5, 4, 3, 2, 1};
#define ATTN_BLOCKS (2207 * 8)

// ---------------- weight convert+transpose: W[K][N] f32 -> Wt[N][K] bf16 (z = layer) ---
__global__ __launch_bounds__(256) void wcvt_k(const float* __restrict__ W,
                                              unsigned short* __restrict__ Wt,
                                              int K, int N)
{
    __shared__ unsigned short tile[64][72];
    size_t ls = (size_t)K * N * blockIdx.z;
    const float* Wl = W + ls;
    unsigned short* Wtl = Wt + ls;
    int k0 = blockIdx.x * 64, n0 = blockIdx.y * 64;
    int t = threadIdx.x;
    int kl = t >> 2, nb = (t & 3) * 16;
    const float* src = Wl + (size_t)(k0 + kl) * N + n0 + nb;
#pragma unroll
    for (int i = 0; i < 4; i++) {
        float4 v = *(const float4*)(src + 4 * i);
        tile[nb + 4 * i + 0][kl] = f2b(v.x);
        tile[nb + 4 * i + 1][kl] = f2b(v.y);
        tile[nb + 4 * i + 2][kl] = f2b(v.z);
        tile[nb + 4 * i + 3][kl] = f2b(v.w);
    }
    __syncthreads();
    int nl = t >> 2, ks = (t & 3) * 16;
    unsigned short* dst = Wtl + (size_t)(n0 + nl) * K + k0 + ks;
    *(uint4*)dst = *(const uint4*)&tile[nl][ks];
    *(uint4*)(dst + 8) = *(const uint4*)&tile[nl][ks + 8];
}

// ---------------- x f32 -> bf16 flat ----------------
__global__ __launch_bounds__(256) void xcvt_k(const float* __restrict__ X,
                                              unsigned short* __restrict__ Xb)
{
    int i = (blockIdx.x * 256 + threadIdx.x) * 8;
    float4 a = *(const float4*)(X + i);
    float4 b = *(const float4*)(X + i + 4);
    unsigned short o[8];
    o[0] = f2b(a.x); o[1] = f2b(a.y); o[2] = f2b(a.z); o[3] = f2b(a.w);
    o[4] = f2b(b.x); o[5] = f2b(b.y); o[6] = f2b(b.z); o[7] = f2b(b.w);
    *(uint4*)(Xb + i) = *(const uint4*)o;
}

// ---------------- dsel[n][k] = distance[n][indices[n][k]] ----------------
__global__ __launch_bounds__(256) void dsel_k(const float* __restrict__ distance,
                                              const int* __restrict__ indices,
                                              float* __restrict__ dsel)
{
    int n = blockIdx.x, t = threadIdx.x;
    if (t < KMAX) {
        int idx = indices[(size_t)n * KMAX + t];
        dsel[(size_t)n * KMAX + t] = distance[(size_t)n * NTOK + idx];
    }
}

// ---------------- kn[n][h] = sum_d K[n,h,d]^2 from bf16 qkv ----------------
__global__ __launch_bounds__(512) void knb_k(const unsigned short* __restrict__ qkv,
                                             float* __restrict__ kn)
{
    int n = blockIdx.x;
    int hh = threadIdx.x >> 6, lane = threadIdx.x & 63;
    float kv = b2f(qkv[(size_t)n * 1536 + 512 + hh * 64 + lane]);
    float ks = wsum(kv * kv);
    if (lane == 0) kn[n * NHEAD + hh] = ks;
}

// ---------------- MFMA GEMM: C = epilogue(A_bf16[M,K] @ Wt_bf16[N,K]^T + bias) -------
// MODE 0: Cf = v
// MODE 1: Cf = resid + relu(v)        (res)
// MODE 2: Cb = bf16(gelu(v))          (fc1)
// MODE 3: Cf = resid + v              (proj, fc2; resid may alias Cf)
// MODE 4: Cf = v and Cb = bf16(v)     (adapter)
// MODE 5: Cb = bf16(v)                (qkv)
template <int MODE>
__global__ __launch_bounds__(256) void mgemm_k(
    const unsigned short* __restrict__ A, const unsigned short* __restrict__ Wt,
    const float* __restrict__ bias, const float* __restrict__ resid,
    float* __restrict__ Cf, unsigned short* __restrict__ Cb,
    int M, int N, int K)
{
    __shared__ unsigned short Asl[64 * 40];
    __shared__ unsigned short Bsl[128 * 40];
    int tid = threadIdx.x;
    int bm = blockIdx.x * 64, bn = blockIdx.y * 128;
    int lane = tid & 63, wid = tid >> 6;
    int wm = wid >> 1, wn = wid & 1;
    int l15 = lane & 15, l4 = lane >> 4;

    f32x4 acc[2][4] = {};

    int ar = tid >> 2, ak = (tid & 3) * 8;
    const unsigned short* Ap  = A  + (size_t)(bm + ar) * K + ak;
    const unsigned short* Bp0 = Wt + (size_t)(bn + ar) * K + ak;
    const unsigned short* Bp1 = Wt + (size_t)(bn + 64 + ar) * K + ak;

    int aoff  = ar * 40 + ak;
    int arow0 = (wm * 32 + l15) * 40 + l4 * 8;
    int brow0 = (wn * 64 + l15) * 40 + l4 * 8;

    for (int k0 = 0; k0 < K; k0 += 32) {
        uint4 av  = *(const uint4*)(Ap + k0);
        uint4 bv0 = *(const uint4*)(Bp0 + k0);
        uint4 bv1 = *(const uint4*)(Bp1 + k0);
        *(uint4*)&Asl[aoff] = av;
        *(uint4*)&Bsl[aoff] = bv0;
        *(uint4*)&Bsl[aoff + 64 * 40] = bv1;
        __syncthreads();
        bf16x8 af[2], bfr[4];
#pragma unroll
        for (int mr = 0; mr < 2; mr++) af[mr] = *(const bf16x8*)&Asl[arow0 + mr * 16 * 40];
#pragma unroll
        for (int nr = 0; nr < 4; nr++) bfr[nr] = *(const bf16x8*)&Bsl[brow0 + nr * 16 * 40];
#pragma unroll
        for (int mr = 0; mr < 2; mr++)
#pragma unroll
            for (int nr = 0; nr < 4; nr++)
                acc[mr][nr] = __builtin_amdgcn_mfma_f32_16x16x32_bf16(af[mr], bfr[nr], acc[mr][nr], 0, 0, 0);
        __syncthreads();
    }

#pragma unroll
    for (int mr = 0; mr < 2; mr++) {
#pragma unroll
        for (int nr = 0; nr < 4; nr++) {
            int col = bn + wn * 64 + nr * 16 + l15;
            float bcol = bias[col];
#pragma unroll
            for (int r = 0; r < 4; r++) {
                int row = bm + wm * 32 + mr * 16 + l4 * 4 + r;
                size_t off = (size_t)row * N + col;
                float v = acc[mr][nr][r] + bcol;
                if (MODE == 0) {
                    Cf[off] = v;
                } else if (MODE == 1) {
                    Cf[off] = resid[off] + fmaxf(v, 0.f);
                } else if (MODE == 2) {
                    float t3 = tanhf(0.7978845608028654f * (v + 0.044715f * v * v * v));
                    Cb[off] = f2b(0.5f * v * (1.f + t3));
                } else if (MODE == 3) {
                    Cf[off] = resid[off] + v;
                } else if (MODE == 4) {
                    Cf[off] = v;
                    Cb[off] = f2b(v);
                } else {
                    Cb[off] = f2b(v);
                }
            }
        }
    }
}

// ---------------- LayerNorm over D=512, one row per block ----------------
template <int OUTB>
__global__ __launch_bounds__(256) void ln_k(
    const float* __restrict__ X, const float* __restrict__ g,
    const float* __restrict__ bta, void* __restrict__ Yv, float eps)
{
    int row = blockIdx.x;
    int tid = threadIdx.x;
    const float* xr = X + (size_t)row * DMODEL;
    float v0 = xr[tid], v1 = xr[tid + 256];
    __shared__ float red[8];
    float s = wsum(v0 + v1);
    int wid = tid >> 6, lane = tid & 63;
    if (lane == 0) red[wid] = s;
    __syncthreads();
    float m = (red[0] + red[1] + red[2] + red[3]) * (1.f / DMODEL);
    float d0 = v0 - m, d1 = v1 - m;
    float sq = wsum(d0 * d0 + d1 * d1);
    if (lane == 0) red[4 + wid] = sq;
    __syncthreads();
    float var = (red[4] + red[5] + red[6] + red[7]) * (1.f / DMODEL);
    float rs = 1.0f / sqrtf(var + eps);
    float y0 = d0 * rs * g[tid] + bta[tid];
    float y1 = d1 * rs * g[tid + 256] + bta[tid + 256];
    if (OUTB) {
        unsigned short* Y = (unsigned short*)Yv;
        Y[(size_t)row * DMODEL + tid] = f2b(y0);
        Y[(size_t)row * DMODEL + tid + 256] = f2b(y1);
    } else {
        float* Y = (float*)Yv;
        Y[(size_t)row * DMODEL + tid] = y0;
        Y[(size_t)row * DMODEL + tid + 256] = y1;
    }
}

// ---------------- gathered attention, bf16 qkv, balanced head->XCD schedule --------
__global__ __launch_bounds__(256) void attn_k(
    const unsigned short* __restrict__ qkv,   // [n][1536] bf16
    const float* __restrict__ kn,             // [n][8]
    const int* __restrict__ indices, const float* __restrict__ dsel,
    const float* __restrict__ lam, unsigned short* __restrict__ xo, int layer)
{
    int xcd = blockIdx.x & 7;
    int t = blockIdx.x >> 3;
    int hh, blk;
    int c0 = g_s0cnt[xcd];
    if (t < c0) {
        hh = g_s0h[xcd]; blk = g_s0base[xcd] + t;
    } else {
        t -= c0;
        int c1 = g_s1cnt[xcd];
        if (t < c1) {
            hh = g_s1h[xcd]; blk = t;
        } else if (xcd == 7 && t - c1 < 1024) {
            hh = 0; blk = t - c1;
        } else {
            return;
        }
    }

    int wid = threadIdx.x >> 6, lane = threadIdx.x & 63;
    int n = blk * 4 + wid;
    int Kh = 32 + 16 * hh + (hh == 7 ? 16 : 0);   // 32..160, all multiples of 16

    __shared__ __align__(16) float qs[4][64];
    __shared__ float asc[4][KMAX];
    __shared__ int   sidx[4][KMAX];

    float qd = b2f(qkv[(size_t)n * 1536 + hh * 64 + lane]);
    qs[wid][lane] = qd;
    float qn2 = wsum(qd * qd);
    float sp = log1pf(expf(lam[layer * NHEAD + hh]));

    const int* irow = indices + (size_t)n * KMAX;
    const float* drow = dsel + (size_t)n * KMAX;

    // ---- Phase A: scores (kn from table), lane = neighbor ----
    float sc[3];
    int   sid[3];
#pragma unroll
    for (int j = 0; j < 3; j++) { sc[j] = -1e30f; sid[j] = 0; }

    const float4* q4 = (const float4*)&qs[wid][0];
#pragma unroll
    for (int j = 0; j < 3; j++) {
        if (j * 64 >= Kh) break;            // wave-uniform
        int kk = j * 64 + lane;
        bool ok = kk < Kh;
        int idx = ok ? irow[kk] : 0;
        sid[j] = idx;
        const uint4* krow = (const uint4*)(qkv + (size_t)idx * 1536 + 512 + hh * 64);
        float dot = 0.f;
#pragma unroll
        for (int c = 0; c < 8; c++) {
            uint4 kv = krow[c];
            const unsigned short* kp = (const unsigned short*)&kv;
            float4 qa = q4[c * 2], qb = q4[c * 2 + 1];
            dot += qa.x * b2f(kp[0]) + qa.y * b2f(kp[1]) + qa.z * b2f(kp[2]) + qa.w * b2f(kp[3])
                 + qb.x * b2f(kp[4]) + qb.y * b2f(kp[5]) + qb.z * b2f(kp[6]) + qb.w * b2f(kp[7]);
        }
        float knv = kn[idx * NHEAD + hh];
        float dd = drow[ok ? kk : 0];
        float dec = expf(-sp * dd) + 1e-6f;
        float s = (dot - 0.5f * (qn2 + knv)) * 0.125f + logf(dec);
        sc[j] = ok ? s : -1e30f;
    }

    // ---- Phase B: softmax in registers ----
    float mx = fmaxf(fmaxf(sc[0], sc[1]), sc[2]);
    mx = wmax(mx);
    float se = 0.f;
#pragma unroll
    for (int j = 0; j < 3; j++) {
        float e = (sc[j] > -1e29f) ? expf(sc[j] - mx) : 0.f;
        sc[j] = e;
        se += e;
    }
    se = wsum(se);
    float inv = 1.f / se;

#pragma unroll
    for (int j = 0; j < 3; j++) {
        int kk = j * 64 + lane;
        if (kk < Kh) {
            asc[wid][kk] = sc[j] * inv;
            sidx[wid][kk] = sid[j];
        }
    }

    // ---- Phase C: PV packed. lane = (neighbor-of-pair, dim-pair); 16 neighbors/iter --
    int half = lane >> 5;        // which neighbor of each pair
    int dp = lane & 31;          // dim pair: dims 2dp, 2dp+1
    const unsigned* vb = (const unsigned*)(qkv + 1024 + hh * 64) + dp;
    float ax = 0.f, ay = 0.f;
    for (int k0 = 0; k0 < Kh; k0 += 16) {
        float aa[8];
        unsigned vv[8];
        int ii[8];
#pragma unroll
        for (int u = 0; u < 8; u++) {
            int kk = k0 + 2 * u + half;
            ii[u] = sidx[wid][kk];
            aa[u] = asc[wid][kk];
        }
#pragma unroll
        for (int u = 0; u < 8; u++) vv[u] = vb[(size_t)ii[u] * 768];
#pragma unroll
        for (int u = 0; u < 8; u++) {
            ax += aa[u] * b2f((unsigned short)(vv[u] & 0xFFFF));
            ay += aa[u] * b2f((unsigned short)(vv[u] >> 16));
        }
    }
    ax += __shfl_xor(ax, 32, 64);
    ay += __shfl_xor(ay, 32, 64);
    if (lane < 32) {
        unsigned o = ((unsigned)f2b(ay) << 16) | (unsigned)f2b(ax);
        *((unsigned*)(xo + (size_t)n * DMODEL + hh * 64) + dp) = o;
    }
}

// ---------------- column partial sums of Y (4096 x 512): 16 rows per block ----------------
__global__ __launch_bounds__(512) void colpart_k(const float* __restrict__ Y, float* __restrict__ part)
{
    int c = threadIdx.x;
    int blk = blockIdx.x;
    const float* p = Y + (size_t)blk * 16 * DMODEL + c;
    float s = 0.f;
#pragma unroll
    for (int r = 0; r < 16; r++) s += p[r * DMODEL];
    part[blk * DMODEL + c] = s;
}

// ---------------- finish mean + head GEMV ----------------
__global__ __launch_bounds__(512) void finhead_k(
    const float* __restrict__ part, const float* __restrict__ head_w,
    const float* __restrict__ head_b, float* __restrict__ out)
{
    __shared__ float mv[DMODEL];
    int c = threadIdx.x;
    float s = 0.f;
    for (int i = 0; i < 256; i++) s += part[i * DMODEL + c];
    mv[c] = s * (1.f / NTOK);
    __syncthreads();
    if (c < 64) {
        float a0 = 0.f, a1 = 0.f;
        for (int d = c; d < DMODEL; d += 64) {
            float m = mv[d];
            a0 += m * head_w[d * NCLS + 0];
            a1 += m * head_w[d * NCLS + 1];
        }
        a0 = wsum(a0);
        a1 = wsum(a1);
        if (c == 0) { out[0] = a0 + head_b[0]; out[1] = a1 + head_b[1]; }
    }
}

extern "C" void kernel_launch(void* const* d_in, const int* in_sizes, int n_in,
                              void* d_out, int out_size, void* d_ws, size_t ws_size,
                              hipStream_t stream)
{
    const float* x        = (const float*)d_in[0];
    const float* distance = (const float*)d_in[1];
    const int*   indices  = (const int*)d_in[2];
    const float* adapter_w = (const float*)d_in[5];
    const float* adapter_b = (const float*)d_in[6];
    const float* res_w     = (const float*)d_in[7];
    const float* res_b     = (const float*)d_in[8];
    const float* ln1_g     = (const float*)d_in[9];
    const float* ln1_b     = (const float*)d_in[10];
    const float* qkv_w     = (const float*)d_in[11];
    const float* qkv_b     = (const float*)d_in[12];
    const float* proj_w    = (const float*)d_in[13];
    const float* proj_b    = (const float*)d_in[14];
    const float* ln2_g     = (const float*)d_in[15];
    const float* ln2_b     = (const float*)d_in[16];
    const float* fc1_w     = (const float*)d_in[17];
    const float* fc1_b     = (const float*)d_in[18];
    const float* fc2_w     = (const float*)d_in[19];
    const float* fc2_b     = (const float*)d_in[20];
    const float* lam       = (const float*)d_in[21];
    const float* lnf_g     = (const float*)d_in[22];
    const float* lnf_b     = (const float*)d_in[23];
    const float* head_w    = (const float*)d_in[24];
    const float* head_b    = (const float*)d_in[25];
    float* out = (float*)d_out;

    char* wsb = (char*)d_ws;
    float* h   = (float*)(wsb);                         // 8 MB
    float* h0  = (float*)(wsb + (8u << 20));            // 8 MB; dead during layers -> dsel
    float* dsel = (float*)(wsb + (8u << 20));           // 2.6 MB
    char* shared = wsb + (16u << 20);                   // 24 MB shared region
    unsigned short* xb    = (unsigned short*)shared;                // 8 MB (dead after adapter)
    unsigned short* qkvbb = (unsigned short*)shared;                // 12 MB bf16
    unsigned short* fc1b  = (unsigned short*)shared;                // 16 MB (after attn)
    unsigned short* adapter_wt = (unsigned short*)(shared + (8u << 20));  // 1 MB
    unsigned short* res_wt     = (unsigned short*)(shared + (9u << 20));  // 0.5 MB
    unsigned short* lnb  = (unsigned short*)(wsb + (40u << 20));    // 4 MB (also h0b)
    unsigned short* h0b  = lnb;
    unsigned short* xob  = (unsigned short*)(wsb + (44u << 20));    // 4 MB
    unsigned short* qkv_wt = (unsigned short*)(wsb + (48u << 20));  // 3 MB
    unsigned short* proj_wt = (unsigned short*)(wsb + (51u << 20)); // 1 MB
    unsigned short* fc1_wt  = (unsigned short*)(wsb + (52u << 20)); // 4 MB
    unsigned short* fc2_wt  = (unsigned short*)(wsb + (56u << 20)); // 4 MB
    float* kn   = (float*)(wsb + (60u << 20));                      // 128 KB
    float* part = (float*)(wsb + (60u << 20) + (1u << 18));         // 512 KB

    dim3 blk(256);

    // --- conversions (batched over layers via z) ---
    xcvt_k<<<(NTOK * EMB) / 2048, blk, 0, stream>>>(x, xb);
    wcvt_k<<<dim3(EMB / 64, DMODEL / 64, 1), blk, 0, stream>>>(adapter_w, adapter_wt, EMB, DMODEL);
    wcvt_k<<<dim3(DMODEL / 64, DMODEL / 64, 1), blk, 0, stream>>>(res_w, res_wt, DMODEL, DMODEL);
    wcvt_k<<<dim3(DMODEL / 64, 1536 / 64, NLAYER), blk, 0, stream>>>(qkv_w, qkv_wt, DMODEL, 1536);
    wcvt_k<<<dim3(DMODEL / 64, DMODEL / 64, NLAYER), blk, 0, stream>>>(proj_w, proj_wt, DMODEL, DMODEL);
    wcvt_k<<<dim3(DMODEL / 64, 2048 / 64, NLAYER), blk, 0, stream>>>(fc1_w, fc1_wt, DMODEL, 2048);
    wcvt_k<<<dim3(2048 / 64, DMODEL / 64, NLAYER), blk, 0, stream>>>(fc2_w, fc2_wt, 2048, DMODEL);

    // --- adapter: h0 = x @ adapter_w + b ---
    mgemm_k<4><<<dim3(NTOK / 64, DMODEL / 128), blk, 0, stream>>>(
        xb, adapter_wt, adapter_b, nullptr, h0, h0b, NTOK, DMODEL, EMB);
    // --- h = h0 + relu(h0 @ res_w + b) ---
    mgemm_k<1><<<dim3(NTOK / 64, DMODEL / 128), blk, 0, stream>>>(
        h0b, res_wt, res_b, h0, h, nullptr, NTOK, DMODEL, DMODEL);

    // dsel: h0 now dead until lnf
    dsel_k<<<NTOK, blk, 0, stream>>>(distance, indices, dsel);

    for (int l = 0; l < NLAYER; l++) {
        ln_k<1><<<NTOK, blk, 0, stream>>>(h, ln1_g + l * DMODEL, ln1_b + l * DMODEL, lnb, 1e-5f);
        mgemm_k<5><<<dim3(NTOK / 64, 1536 / 128), blk, 0, stream>>>(
            lnb, qkv_wt + (size_t)l * 1536 * DMODEL, qkv_b + l * 1536, nullptr,
            nullptr, qkvbb, NTOK, 1536, DMODEL);
        knb_k<<<NTOK, 512, 0, stream>>>(qkvbb, kn);
        attn_k<<<ATTN_BLOCKS, blk, 0, stream>>>(qkvbb, kn, indices, dsel, lam, xob, l);
        mgemm_k<3><<<dim3(NTOK / 64, DMODEL / 128), blk, 0, stream>>>(
            xob, proj_wt + (size_t)l * DMODEL * DMODEL, proj_b + l * DMODEL, h,
            h, nullptr, NTOK, DMODEL, DMODEL);
        ln_k<1><<<NTOK, blk, 0, stream>>>(h, ln2_g + l * DMODEL, ln2_b + l * DMODEL, lnb, 1e-5f);
        mgemm_k<2><<<dim3(NTOK / 64, 2048 / 128), blk, 0, stream>>>(
            lnb, fc1_wt + (size_t)l * 2048 * DMODEL, fc1_b + l * 2048, nullptr,
            nullptr, fc1b, NTOK, 2048, DMODEL);
        mgemm_k<3><<<dim3(NTOK / 64, DMODEL / 128), blk, 0, stream>>>(
            fc1b, fc2_wt + (size_t)l * DMODEL * 2048, fc2_b + l * DMODEL, h,
            h, nullptr, NTOK, DMODEL, 2048);
    }

    ln_k<0><<<NTOK, blk, 0, stream>>>(h, lnf_g, lnf_b, h0, 1e-6f);
    colpart_k<<<256, 512, 0, stream>>>(h0, part);
    finhead_k<<<1, 512, 0, stream>>>(part, head_w, head_b, out);
}

// Round 6
// 481.053 us; speedup vs baseline: 4.6146x; 1.0070x over previous
//
#include <hip/hip_runtime.h>
#include <hip/hip_bf16.h>

#define NTOK 4096
#define EMB 1024
#define DMODEL 512
#define NHEAD 8
#define NLAYER 2
#define NCLS 2
#define KMAX 160

typedef __attribute__((ext_vector_type(8))) short bf16x8;
typedef __attribute__((ext_vector_type(4))) float f32x4;

__device__ inline unsigned short f2b(float f) {
    unsigned u = __float_as_uint(f);
    u = u + 0x7FFFu + ((u >> 16) & 1u);
    return (unsigned short)(u >> 16);
}
__device__ inline float b2f(unsigned short s) {
    return __uint_as_float((unsigned)s << 16);
}

__device__ inline float wsum(float v) {
    for (int o = 32; o > 0; o >>= 1) v += __shfl_xor(v, o, 64);
    return v;
}
__device__ inline float wmax(float v) {
    for (int o = 32; o > 0; o >>= 1) v = fmaxf(v, __shfl_xor(v, o, 64));
    return v;
}

// async global->LDS, 16 B per lane. dest must be wave-uniform base + lane*16.
typedef __attribute__((address_space(3))) unsigned lds_u32_t;
typedef __attribute__((address_space(1))) const unsigned glb_u32_t;
__device__ inline void gload16(const void* g, void* l) {
    __builtin_amdgcn_global_load_lds((glb_u32_t*)(unsigned long long)g,
                                     (lds_u32_t*)(unsigned)(unsigned long long)l,
                                     16, 0, 0);
}

// Balanced head->XCD schedule: work blocks of 4 rows, 1024 blocks/head.
__device__ const int g_s0cnt[8]  = {576, 448, 720, 144, 365, 490, 460, 159};
__device__ const int g_s0h[8]    = {7, 7, 6, 6, 5, 4, 3, 2};
__device__ const int g_s0base[8] = {0, 576, 160, 880, 659, 534, 564, 865};
__device__ const int g_s1cnt[8]  = {0, 160, 0, 659, 534, 564, 865, 1024};
__device__ const int g_s1h[8]    = {0, 6, 0, 5, 4, 3, 2, 1};
#define ATTN_BLOCKS (2207 * 8)

// ---------------- weight convert+transpose: W[K][N] f32 -> Wt[N][K] bf16 (z = layer) ---
__global__ __launch_bounds__(256) void wcvt_k(const float* __restrict__ W,
                                              unsigned short* __restrict__ Wt,
                                              int K, int N)
{
    __shared__ unsigned short tile[64][72];
    size_t ls = (size_t)K * N * blockIdx.z;
    const float* Wl = W + ls;
    unsigned short* Wtl = Wt + ls;
    int k0 = blockIdx.x * 64, n0 = blockIdx.y * 64;
    int t = threadIdx.x;
    int kl = t >> 2, nb = (t & 3) * 16;
    const float* src = Wl + (size_t)(k0 + kl) * N + n0 + nb;
#pragma unroll
    for (int i = 0; i < 4; i++) {
        float4 v = *(const float4*)(src + 4 * i);
        tile[nb + 4 * i + 0][kl] = f2b(v.x);
        tile[nb + 4 * i + 1][kl] = f2b(v.y);
        tile[nb + 4 * i + 2][kl] = f2b(v.z);
        tile[nb + 4 * i + 3][kl] = f2b(v.w);
    }
    __syncthreads();
    int nl = t >> 2, ks = (t & 3) * 16;
    unsigned short* dst = Wtl + (size_t)(n0 + nl) * K + k0 + ks;
    *(uint4*)dst = *(const uint4*)&tile[nl][ks];
    *(uint4*)(dst + 8) = *(const uint4*)&tile[nl][ks + 8];
}

// ---------------- x f32 -> bf16 flat ----------------
__global__ __launch_bounds__(256) void xcvt_k(const float* __restrict__ X,
                                              unsigned short* __restrict__ Xb)
{
    int i = (blockIdx.x * 256 + threadIdx.x) * 8;
    float4 a = *(const float4*)(X + i);
    float4 b = *(const float4*)(X + i + 4);
    unsigned short o[8];
    o[0] = f2b(a.x); o[1] = f2b(a.y); o[2] = f2b(a.z); o[3] = f2b(a.w);
    o[4] = f2b(b.x); o[5] = f2b(b.y); o[6] = f2b(b.z); o[7] = f2b(b.w);
    *(uint4*)(Xb + i) = *(const uint4*)o;
}

// ---------------- dsel[n][k] = distance[n][indices[n][k]] ----------------
__global__ __launch_bounds__(256) void dsel_k(const float* __restrict__ distance,
                                              const int* __restrict__ indices,
                                              float* __restrict__ dsel)
{
    int n = blockIdx.x, t = threadIdx.x;
    if (t < KMAX) {
        int idx = indices[(size_t)n * KMAX + t];
        dsel[(size_t)n * KMAX + t] = distance[(size_t)n * NTOK + idx];
    }
}

// ---------------- kn[n][h] = sum_d K[n,h,d]^2 from bf16 qkv ----------------
__global__ __launch_bounds__(512) void knb_k(const unsigned short* __restrict__ qkv,
                                             float* __restrict__ kn)
{
    int n = blockIdx.x;
    int hh = threadIdx.x >> 6, lane = threadIdx.x & 63;
    float kv = b2f(qkv[(size_t)n * 1536 + 512 + hh * 64 + lane]);
    float ks = wsum(kv * kv);
    if (lane == 0) kn[n * NHEAD + hh] = ks;
}

// ---------------- MFMA GEMM (m97 structure): C = epi(A_bf16[M,K] @ Wt[N,K]^T + bias) --
// Tile BM x BN, waves WM x WN, BK=32, global_load_lds staging, linear LDS.
// MODE 0: Cf=v  1: Cf=resid+relu(v)  2: Cb=bf16(gelu(v))  3: Cf=resid+v
// MODE 4: Cf=v, Cb=bf16(v)  5: Cb=bf16(v)
template <int BM, int BN, int WM, int WN, int MODE>
__global__ __launch_bounds__(256) void mgemm_k(
    const unsigned short* __restrict__ A, const unsigned short* __restrict__ Wt,
    const float* __restrict__ bias, const float* __restrict__ resid,
    float* __restrict__ Cf, unsigned short* __restrict__ Cb,
    int M, int N, int K)
{
    constexpr int SM = BM / WM;          // wave sub-tile rows
    constexpr int SN = BN / WN;          // wave sub-tile cols
    constexpr int MR = SM / 16;
    constexpr int NR = SN / 16;

    __shared__ unsigned short Asl[BM * 32];
    __shared__ unsigned short Bsl[BN * 32];

    int tid = threadIdx.x;
    int bm = blockIdx.x * BM, bn = blockIdx.y * BN;
    int lane = tid & 63, wid = tid >> 6;
    int wm = wid / WN, wn = wid % WN;
    int l15 = lane & 15, l4 = lane >> 4;

    f32x4 acc[MR][NR] = {};

    int sr = tid >> 2, sc = (tid & 3) * 8;              // staging row/col
    const unsigned short* Asrc = A  + (size_t)(bm + sr) * K + sc;
    const unsigned short* Bsrc = Wt + (size_t)(bn + sr) * K + sc;
    unsigned short* Adst = &Asl[sr * 32 + sc];
    unsigned short* Bdst = &Bsl[sr * 32 + sc];

    int arow0 = (wm * SM + l15) * 32 + l4 * 8;
    int brow0 = (wn * SN + l15) * 32 + l4 * 8;

    for (int k0 = 0; k0 < K; k0 += 32) {
#pragma unroll
        for (int i = 0; i < BM / 64; i++)
            gload16(Asrc + (size_t)(i * 64) * K + k0, Adst + i * 64 * 32);
#pragma unroll
        for (int i = 0; i < BN / 64; i++)
            gload16(Bsrc + (size_t)(i * 64) * K + k0, Bdst + i * 64 * 32);
        __syncthreads();     // drains vmcnt(0) before barrier

        bf16x8 af[MR], bfr[NR];
#pragma unroll
        for (int mr = 0; mr < MR; mr++) af[mr] = *(const bf16x8*)&Asl[arow0 + mr * 16 * 32];
#pragma unroll
        for (int nr = 0; nr < NR; nr++) bfr[nr] = *(const bf16x8*)&Bsl[brow0 + nr * 16 * 32];
#pragma unroll
        for (int mr = 0; mr < MR; mr++)
#pragma unroll
            for (int nr = 0; nr < NR; nr++)
                acc[mr][nr] = __builtin_amdgcn_mfma_f32_16x16x32_bf16(af[mr], bfr[nr], acc[mr][nr], 0, 0, 0);
        __syncthreads();
    }

#pragma unroll
    for (int mr = 0; mr < MR; mr++) {
#pragma unroll
        for (int nr = 0; nr < NR; nr++) {
            int col = bn + wn * SN + nr * 16 + l15;
            float bcol = bias[col];
#pragma unroll
            for (int r = 0; r < 4; r++) {
                int row = bm + wm * SM + mr * 16 + l4 * 4 + r;
                size_t off = (size_t)row * N + col;
                float v = acc[mr][nr][r] + bcol;
                if (MODE == 0) {
                    Cf[off] = v;
                } else if (MODE == 1) {
                    Cf[off] = resid[off] + fmaxf(v, 0.f);
                } else if (MODE == 2) {
                    float t3 = tanhf(0.7978845608028654f * (v + 0.044715f * v * v * v));
                    Cb[off] = f2b(0.5f * v * (1.f + t3));
                } else if (MODE == 3) {
                    Cf[off] = resid[off] + v;
                } else if (MODE == 4) {
                    Cf[off] = v;
                    Cb[off] = f2b(v);
                } else {
                    Cb[off] = f2b(v);
                }
            }
        }
    }
}

// ---------------- LayerNorm over D=512, one row per block ----------------
template <int OUTB>
__global__ __launch_bounds__(256) void ln_k(
    const float* __restrict__ X, const float* __restrict__ g,
    const float* __restrict__ bta, void* __restrict__ Yv, float eps)
{
    int row = blockIdx.x;
    int tid = threadIdx.x;
    const float* xr = X + (size_t)row * DMODEL;
    float v0 = xr[tid], v1 = xr[tid + 256];
    __shared__ float red[8];
    float s = wsum(v0 + v1);
    int wid = tid >> 6, lane = tid & 63;
    if (lane == 0) red[wid] = s;
    __syncthreads();
    float m = (red[0] + red[1] + red[2] + red[3]) * (1.f / DMODEL);
    float d0 = v0 - m, d1 = v1 - m;
    float sq = wsum(d0 * d0 + d1 * d1);
    if (lane == 0) red[4 + wid] = sq;
    __syncthreads();
    float var = (red[4] + red[5] + red[6] + red[7]) * (1.f / DMODEL);
    float rs = 1.0f / sqrtf(var + eps);
    float y0 = d0 * rs * g[tid] + bta[tid];
    float y1 = d1 * rs * g[tid + 256] + bta[tid + 256];
    if (OUTB) {
        unsigned short* Y = (unsigned short*)Yv;
        Y[(size_t)row * DMODEL + tid] = f2b(y0);
        Y[(size_t)row * DMODEL + tid + 256] = f2b(y1);
    } else {
        float* Y = (float*)Yv;
        Y[(size_t)row * DMODEL + tid] = y0;
        Y[(size_t)row * DMODEL + tid + 256] = y1;
    }
}

// ---------------- gathered attention, bf16 qkv, balanced head->XCD schedule --------
__global__ __launch_bounds__(256) void attn_k(
    const unsigned short* __restrict__ qkv,   // [n][1536] bf16
    const float* __restrict__ kn,             // [n][8]
    const int* __restrict__ indices, const float* __restrict__ dsel,
    const float* __restrict__ lam, unsigned short* __restrict__ xo, int layer)
{
    int xcd = blockIdx.x & 7;
    int t = blockIdx.x >> 3;
    int hh, blk;
    int c0 = g_s0cnt[xcd];
    if (t < c0) {
        hh = g_s0h[xcd]; blk = g_s0base[xcd] + t;
    } else {
        t -= c0;
        int c1 = g_s1cnt[xcd];
        if (t < c1) {
            hh = g_s1h[xcd]; blk = t;
        } else if (xcd == 7 && t - c1 < 1024) {
            hh = 0; blk = t - c1;
        } else {
            return;
        }
    }

    int wid = threadIdx.x >> 6, lane = threadIdx.x & 63;
    int n = blk * 4 + wid;
    int Kh = 32 + 16 * hh + (hh == 7 ? 16 : 0);   // 32..160

    __shared__ __align__(16) float qs[4][64];
    __shared__ float asc[4][KMAX];
    __shared__ int   sidx[4][KMAX];

    float qd = b2f(qkv[(size_t)n * 1536 + hh * 64 + lane]);
    qs[wid][lane] = qd;
    float qn2 = wsum(qd * qd);
    float sp = log1pf(expf(lam[layer * NHEAD + hh]));

    const int* irow = indices + (size_t)n * KMAX;
    const float* drow = dsel + (size_t)n * KMAX;

    // ---- Phase A: scores (kn from table), lane = neighbor ----
    float sc[3];
    int   sid[3];
#pragma unroll
    for (int j = 0; j < 3; j++) { sc[j] = -1e30f; sid[j] = 0; }

    const float4* q4 = (const float4*)&qs[wid][0];
#pragma unroll
    for (int j = 0; j < 3; j++) {
        if (j * 64 >= Kh) break;            // wave-uniform
        int kk = j * 64 + lane;
        bool ok = kk < Kh;
        int idx = ok ? irow[kk] : 0;
        sid[j] = idx;
        const uint4* krow = (const uint4*)(qkv + (size_t)idx * 1536 + 512 + hh * 64);
        float dot = 0.f;
#pragma unroll
        for (int c = 0; c < 8; c++) {
            uint4 kv = krow[c];
            const unsigned short* kp = (const unsigned short*)&kv;
            float4 qa = q4[c * 2], qb = q4[c * 2 + 1];
            dot += qa.x * b2f(kp[0]) + qa.y * b2f(kp[1]) + qa.z * b2f(kp[2]) + qa.w * b2f(kp[3])
                 + qb.x * b2f(kp[4]) + qb.y * b2f(kp[5]) + qb.z * b2f(kp[6]) + qb.w * b2f(kp[7]);
        }
        float knv = kn[idx * NHEAD + hh];
        float dd = drow[ok ? kk : 0];
        float dec = expf(-sp * dd) + 1e-6f;
        float s = (dot - 0.5f * (qn2 + knv)) * 0.125f + logf(dec);
        sc[j] = ok ? s : -1e30f;
    }

    // ---- Phase B: softmax in registers ----
    float mx = fmaxf(fmaxf(sc[0], sc[1]), sc[2]);
    mx = wmax(mx);
    float se = 0.f;
#pragma unroll
    for (int j = 0; j < 3; j++) {
        float e = (sc[j] > -1e29f) ? expf(sc[j] - mx) : 0.f;
        sc[j] = e;
        se += e;
    }
    se = wsum(se);
    float inv = 1.f / se;

#pragma unroll
    for (int j = 0; j < 3; j++) {
        int kk = j * 64 + lane;
        if (kk < Kh) {
            asc[wid][kk] = sc[j] * inv;
            sidx[wid][kk] = sid[j];
        }
    }

    // ---- Phase C: PV packed. lane = (neighbor-of-pair, dim-pair); 16 neighbors/iter --
    int half = lane >> 5;
    int dp = lane & 31;
    const unsigned* vb = (const unsigned*)(qkv + 1024 + hh * 64) + dp;
    float ax = 0.f, ay = 0.f;
    for (int k0 = 0; k0 < Kh; k0 += 16) {
        float aa[8];
        unsigned vv[8];
        int ii[8];
#pragma unroll
        for (int u = 0; u < 8; u++) {
            int kk = k0 + 2 * u + half;
            ii[u] = sidx[wid][kk];
            aa[u] = asc[wid][kk];
        }
#pragma unroll
        for (int u = 0; u < 8; u++) vv[u] = vb[(size_t)ii[u] * 768];
#pragma unroll
        for (int u = 0; u < 8; u++) {
            ax += aa[u] * b2f((unsigned short)(vv[u] & 0xFFFF));
            ay += aa[u] * b2f((unsigned short)(vv[u] >> 16));
        }
    }
    ax += __shfl_xor(ax, 32, 64);
    ay += __shfl_xor(ay, 32, 64);
    if (lane < 32) {
        unsigned o = ((unsigned)f2b(ay) << 16) | (unsigned)f2b(ax);
        *((unsigned*)(xo + (size_t)n * DMODEL + hh * 64) + dp) = o;
    }
}

// ---------------- column partial sums ----------------
__global__ __launch_bounds__(512) void colpart_k(const float* __restrict__ Y, float* __restrict__ part)
{
    int c = threadIdx.x;
    int blk = blockIdx.x;
    const float* p = Y + (size_t)blk * 16 * DMODEL + c;
    float s = 0.f;
#pragma unroll
    for (int r = 0; r < 16; r++) s += p[r * DMODEL];
    part[blk * DMODEL + c] = s;
}

// ---------------- finish mean + head GEMV ----------------
__global__ __launch_bounds__(512) void finhead_k(
    const float* __restrict__ part, const float* __restrict__ head_w,
    const float* __restrict__ head_b, float* __restrict__ out)
{
    __shared__ float mv[DMODEL];
    int c = threadIdx.x;
    float s = 0.f;
    for (int i = 0; i < 256; i++) s += part[i * DMODEL + c];
    mv[c] = s * (1.f / NTOK);
    __syncthreads();
    if (c < 64) {
        float a0 = 0.f, a1 = 0.f;
        for (int d = c; d < DMODEL; d += 64) {
            float m = mv[d];
            a0 += m * head_w[d * NCLS + 0];
            a1 += m * head_w[d * NCLS + 1];
        }
        a0 = wsum(a0);
        a1 = wsum(a1);
        if (c == 0) { out[0] = a0 + head_b[0]; out[1] = a1 + head_b[1]; }
    }
}

extern "C" void kernel_launch(void* const* d_in, const int* in_sizes, int n_in,
                              void* d_out, int out_size, void* d_ws, size_t ws_size,
                              hipStream_t stream)
{
    const float* x        = (const float*)d_in[0];
    const float* distance = (const float*)d_in[1];
    const int*   indices  = (const int*)d_in[2];
    const float* adapter_w = (const float*)d_in[5];
    const float* adapter_b = (const float*)d_in[6];
    const float* res_w     = (const float*)d_in[7];
    const float* res_b     = (const float*)d_in[8];
    const float* ln1_g     = (const float*)d_in[9];
    const float* ln1_b     = (const float*)d_in[10];
    const float* qkv_w     = (const float*)d_in[11];
    const float* qkv_b     = (const float*)d_in[12];
    const float* proj_w    = (const float*)d_in[13];
    const float* proj_b    = (const float*)d_in[14];
    const float* ln2_g     = (const float*)d_in[15];
    const float* ln2_b     = (const float*)d_in[16];
    const float* fc1_w     = (const float*)d_in[17];
    const float* fc1_b     = (const float*)d_in[18];
    const float* fc2_w     = (const float*)d_in[19];
    const float* fc2_b     = (const float*)d_in[20];
    const float* lam       = (const float*)d_in[21];
    const float* lnf_g     = (const float*)d_in[22];
    const float* lnf_b     = (const float*)d_in[23];
    const float* head_w    = (const float*)d_in[24];
    const float* head_b    = (const float*)d_in[25];
    float* out = (float*)d_out;

    char* wsb = (char*)d_ws;
    float* h   = (float*)(wsb);                         // 8 MB
    float* h0  = (float*)(wsb + (8u << 20));            // 8 MB; dead during layers -> dsel
    float* dsel = (float*)(wsb + (8u << 20));           // 2.6 MB
    char* shared = wsb + (16u << 20);                   // 24 MB shared region
    unsigned short* xb    = (unsigned short*)shared;                // 8 MB (dead after adapter)
    unsigned short* qkvbb = (unsigned short*)shared;                // 12 MB bf16
    unsigned short* fc1b  = (unsigned short*)shared;                // 16 MB (after attn)
    unsigned short* adapter_wt = (unsigned short*)(shared + (8u << 20));  // 1 MB
    unsigned short* res_wt     = (unsigned short*)(shared + (9u << 20));  // 0.5 MB
    unsigned short* lnb  = (unsigned short*)(wsb + (40u << 20));    // 4 MB (also h0b)
    unsigned short* h0b  = lnb;
    unsigned short* xob  = (unsigned short*)(wsb + (44u << 20));    // 4 MB
    unsigned short* qkv_wt = (unsigned short*)(wsb + (48u << 20));  // 3 MB
    unsigned short* proj_wt = (unsigned short*)(wsb + (51u << 20)); // 1 MB
    unsigned short* fc1_wt  = (unsigned short*)(wsb + (52u << 20)); // 4 MB
    unsigned short* fc2_wt  = (unsigned short*)(wsb + (56u << 20)); // 4 MB
    float* kn   = (float*)(wsb + (60u << 20));                      // 128 KB
    float* part = (float*)(wsb + (60u << 20) + (1u << 18));         // 512 KB

    dim3 blk(256);

    // --- conversions (batched over layers via z) ---
    xcvt_k<<<(NTOK * EMB) / 2048, blk, 0, stream>>>(x, xb);
    wcvt_k<<<dim3(EMB / 64, DMODEL / 64, 1), blk, 0, stream>>>(adapter_w, adapter_wt, EMB, DMODEL);
    wcvt_k<<<dim3(DMODEL / 64, DMODEL / 64, 1), blk, 0, stream>>>(res_w, res_wt, DMODEL, DMODEL);
    wcvt_k<<<dim3(DMODEL / 64, 1536 / 64, NLAYER), blk, 0, stream>>>(qkv_w, qkv_wt, DMODEL, 1536);
    wcvt_k<<<dim3(DMODEL / 64, DMODEL / 64, NLAYER), blk, 0, stream>>>(proj_w, proj_wt, DMODEL, DMODEL);
    wcvt_k<<<dim3(DMODEL / 64, 2048 / 64, NLAYER), blk, 0, stream>>>(fc1_w, fc1_wt, DMODEL, 2048);
    wcvt_k<<<dim3(2048 / 64, DMODEL / 64, NLAYER), blk, 0, stream>>>(fc2_w, fc2_wt, 2048, DMODEL);

    // --- adapter: h0 = x @ adapter_w + b ---
    mgemm_k<128, 64, 4, 1, 4><<<dim3(NTOK / 128, DMODEL / 64), blk, 0, stream>>>(
        xb, adapter_wt, adapter_b, nullptr, h0, h0b, NTOK, DMODEL, EMB);
    // --- h = h0 + relu(h0 @ res_w + b) ---
    mgemm_k<128, 64, 4, 1, 1><<<dim3(NTOK / 128, DMODEL / 64), blk, 0, stream>>>(
        h0b, res_wt, res_b, h0, h, nullptr, NTOK, DMODEL, DMODEL);

    // dsel: h0 now dead until lnf
    dsel_k<<<NTOK, blk, 0, stream>>>(distance, indices, dsel);

    for (int l = 0; l < NLAYER; l++) {
        ln_k<1><<<NTOK, blk, 0, stream>>>(h, ln1_g + l * DMODEL, ln1_b + l * DMODEL, lnb, 1e-5f);
        mgemm_k<128, 128, 2, 2, 5><<<dim3(NTOK / 128, 1536 / 128), blk, 0, stream>>>(
            lnb, qkv_wt + (size_t)l * 1536 * DMODEL, qkv_b + l * 1536, nullptr,
            nullptr, qkvbb, NTOK, 1536, DMODEL);
        knb_k<<<NTOK, 512, 0, stream>>>(qkvbb, kn);
        attn_k<<<ATTN_BLOCKS, blk, 0, stream>>>(qkvbb, kn, indices, dsel, lam, xob, l);
        mgemm_k<128, 64, 4, 1, 3><<<dim3(NTOK / 128, DMODEL / 64), blk, 0, stream>>>(
            xob, proj_wt + (size_t)l * DMODEL * DMODEL, proj_b + l * DMODEL, h,
            h, nullptr, NTOK, DMODEL, DMODEL);
        ln_k<1><<<NTOK, blk, 0, stream>>>(h, ln2_g + l * DMODEL, ln2_b + l * DMODEL, lnb, 1e-5f);
        mgemm_k<128, 128, 2, 2, 2><<<dim3(NTOK / 128, 2048 / 128), blk, 0, stream>>>(
            lnb, fc1_wt + (size_t)l * 2048 * DMODEL, fc1_b + l * 2048, nullptr,
            nullptr, fc1b, NTOK, 2048, DMODEL);
        mgemm_k<128, 64, 4, 1, 3><<<dim3(NTOK / 128, DMODEL / 64), blk, 0, stream>>>(
            fc1b, fc2_wt + (size_t)l * DMODEL * 2048, fc2_b + l * DMODEL, h,
            h, nullptr, NTOK, DMODEL, 2048);
    }

    ln_k<0><<<NTOK, blk, 0, stream>>>(h, lnf_g, lnf_b, h0, 1e-6f);
    colpart_k<<<256, 512, 0, stream>>>(h0, part);
    finhead_k<<<1, 512, 0, stream>>>(part, head_w, head_b, out);
}